// Round 9
// baseline (988.929 us; speedup 1.0000x reference)
//
#include <hip/hip_runtime.h>
#include <hip/hip_bf16.h>
#include <math.h>

#define NN 100000
#define NE 1280000
#define NG 256
#define HID 128
#define EMB 64
#define BN_EPS 1e-5f
#define SB 1024
#define SNB ((NN + SB - 1) / SB)   // 98
#define NBG 1563                   // gemm/pool blocks per side (64 rows/block)
#define GBLK 25000                 // gather blocks per side (4 nodes/block)
#define NSB 782                    // stats blocks per side (128 rows/block)
#define PART ((NN + 7) / 8)        // 12500 dsts per XCD partition
#define FCH 2048                   // edges per fill chunk
#define NCH (NE / FCH)             // 625

typedef __attribute__((ext_vector_type(8))) __bf16 bf16x8;
typedef __attribute__((ext_vector_type(4))) float f32x4;

// ---------------------------------------------------------------- bf16 helpers (manual, RNE)
__device__ __forceinline__ float bf2f(unsigned int u) { return __uint_as_float(u << 16); }
__device__ __forceinline__ unsigned int f2b(float f) {
    unsigned int u = __float_as_uint(f);
    return (u + 0x7fffu + ((u >> 16) & 1u)) >> 16;
}

// ---------------------------------------------------------------- utilities
__global__ void detect_i64_kernel(const void* __restrict__ ei, int* __restrict__ flag) {
    if (threadIdx.x == 0 && blockIdx.x == 0) {
        const unsigned long long* p = (const unsigned long long*)ei;
        int is64 = 1;
        #pragma unroll
        for (int i = 0; i < 16; ++i)
            if (p[i] >= (1ull << 32)) is64 = 0;
        *flag = is64;
    }
}

__device__ __forceinline__ int load_idx(const void* p, int i, bool is64) {
    return is64 ? (int)((const long long*)p)[i] : ((const int*)p)[i];
}

// ---------------------------------------------------------------- x -> bf16 (both sides)
__global__ __launch_bounds__(256) void convert_x(const float* __restrict__ x1,
                                                 const float* __restrict__ x2,
                                                 ushort* __restrict__ o1,
                                                 ushort* __restrict__ o2) {
    const int per = NN * 16;
    const int i = blockIdx.x * 256 + threadIdx.x;
    const int side = i >= per;
    const int j = i - side * per;
    const float4 v = ((const float4*)(side ? x2 : x1))[j];
    ushort4 o;
    o.x = (ushort)f2b(v.x); o.y = (ushort)f2b(v.y);
    o.z = (ushort)f2b(v.z); o.w = (ushort)f2b(v.w);
    ((ushort4*)(side ? o2 : o1))[j] = o;
}

// ---------------------------------------------------------------- weights -> bf16 transposed WT[c][k]
__global__ __launch_bounds__(256) void prep_weights(const float* __restrict__ W1,
                                                    const float* __restrict__ W2,
                                                    const float* __restrict__ W3,
                                                    ushort* __restrict__ T1,
                                                    ushort* __restrict__ T2,
                                                    ushort* __restrict__ T3) {
    const int i = blockIdx.x * 256 + threadIdx.x;   // 40960 total
    if (i < 8192) {                 // W1: [64][128]
        const int k = i >> 7, c = i & 127;
        T1[c * 64 + k] = (ushort)f2b(W1[i]);
    } else if (i < 24576) {         // W2: [128][128]
        const int j = i - 8192, k = j >> 7, c = j & 127;
        T2[c * 128 + k] = (ushort)f2b(W2[j]);
    } else if (i < 40960) {         // W3
        const int j = i - 24576, k = j >> 7, c = j & 127;
        T3[c * 128 + k] = (ushort)f2b(W3[j]);
    }
}

// ---------------------------------------------------------------- CSR build
// hist, dst-partitioned (atomics stay XCD-local; same mapping as fill)
__global__ __launch_bounds__(256) void csr_hist_part(const void* __restrict__ e1,
                                                     const void* __restrict__ e2,
                                                     int* __restrict__ degA,
                                                     int* __restrict__ degB,
                                                     const int* __restrict__ flag) {
    const bool is64 = (*flag != 0);
    const int g = blockIdx.x & 7;
    const int q = blockIdx.x >> 3;
    const int side = q >= NCH;
    const int chunk = q - side * NCH;
    const void* __restrict__ e = side ? e2 : e1;
    int* __restrict__ deg = side ? degB : degA;
    const int lo = g * PART;
    const int hi = min(lo + PART, NN);
    const int base = chunk * FCH;
    for (int i = base + threadIdx.x; i < base + FCH; i += 256) {
        const int d = load_idx(e, NE + i, is64);
        if (d >= lo && d < hi) atomicAdd(&deg[d], 1);
    }
}

__global__ __launch_bounds__(256) void scan_block_sums2(const int* __restrict__ degA,
                                                        const int* __restrict__ degB,
                                                        int* __restrict__ bsum) {
    const int side = blockIdx.x >= SNB;
    const int bx = blockIdx.x - side * SNB;
    const int* deg = side ? degB : degA;
    const int t = threadIdx.x;
    const int base = bx * SB + t * 4;
    int s = 0;
    #pragma unroll
    for (int k = 0; k < 4; ++k) {
        const int i = base + k;
        if (i < NN) s += deg[i];
    }
    __shared__ int red[256];
    red[t] = s;
    __syncthreads();
    for (int off = 128; off > 0; off >>= 1) {
        if (t < off) red[t] += red[t + off];
        __syncthreads();
    }
    if (t == 0) bsum[side * 128 + bx] = red[0];
}

__global__ __launch_bounds__(128) void scan_bsums2(const int* __restrict__ bsum,
                                                   int* __restrict__ boff,
                                                   int* __restrict__ rpA,
                                                   int* __restrict__ rpB) {
    const int side = blockIdx.x;
    __shared__ int s[128];
    const int t = threadIdx.x;
    s[t] = (t < SNB) ? bsum[side * 128 + t] : 0;
    __syncthreads();
    for (int off = 1; off < 128; off <<= 1) {
        const int v = (t >= off) ? s[t - off] : 0;
        __syncthreads();
        s[t] += v;
        __syncthreads();
    }
    boff[side * 128 + t] = (t == 0) ? 0 : s[t - 1];
    if (t == 0) (side ? rpB : rpA)[NN] = s[SNB - 1];
}

__global__ __launch_bounds__(256) void scan_fill2(const int* __restrict__ degA,
                                                  const int* __restrict__ degB,
                                                  const int* __restrict__ boff,
                                                  int* __restrict__ rpA,
                                                  int* __restrict__ rpB,
                                                  int* __restrict__ curA,
                                                  int* __restrict__ curB) {
    const int side = blockIdx.x >= SNB;
    const int bx = blockIdx.x - side * SNB;
    const int* deg = side ? degB : degA;
    int* rowptr = side ? rpB : rpA;
    int* cursor = side ? curB : curA;
    const int t = threadIdx.x;
    const int base = bx * SB + t * 4;
    int v[4], s = 0;
    #pragma unroll
    for (int k = 0; k < 4; ++k) {
        const int i = base + k;
        v[k] = (i < NN) ? deg[i] : 0;
        s += v[k];
    }
    __shared__ int red[256];
    red[t] = s;
    __syncthreads();
    for (int off = 1; off < 256; off <<= 1) {
        const int x = (t >= off) ? red[t - off] : 0;
        __syncthreads();
        red[t] += x;
        __syncthreads();
    }
    int run = boff[side * 128 + bx] + ((t == 0) ? 0 : red[t - 1]);
    #pragma unroll
    for (int k = 0; k < 4; ++k) {
        const int i = base + k;
        if (i < NN) {
            rowptr[i] = run;
            cursor[i] = run;
            run += v[k];
        }
    }
}

// fill, dst-partitioned so each col region is written by one XCD
__global__ __launch_bounds__(256) void csr_fill_part(const void* __restrict__ e1,
                                                     const void* __restrict__ e2,
                                                     int* __restrict__ curA,
                                                     int* __restrict__ curB,
                                                     int* __restrict__ colA,
                                                     int* __restrict__ colB,
                                                     const int* __restrict__ flag) {
    const bool is64 = (*flag != 0);
    const int g = blockIdx.x & 7;
    const int q = blockIdx.x >> 3;
    const int side = q >= NCH;
    const int chunk = q - side * NCH;
    const void* __restrict__ e = side ? e2 : e1;
    int* __restrict__ cur = side ? curB : curA;
    int* __restrict__ col = side ? colB : colA;
    const int lo = g * PART;
    const int hi = min(lo + PART, NN);
    const int base = chunk * FCH;
    for (int i = base + threadIdx.x; i < base + FCH; i += 256) {
        const int d = load_idx(e, NE + i, is64);
        if (d >= lo && d < hi) {
            const int pos = atomicAdd(&cur[d], 1);
            col[pos] = load_idx(e, i, is64);
        }
    }
}

// ---------------------------------------------------------------- layer-1 gather (F=64, pure sum)
// one node per wave; lanes split: 0-31 edge e, 32-63 edge e+1; each lane 1 uint (2 cols)
struct G64Args {
    const ushort *xA, *xB;
    const int *rpA, *rpB, *colA, *colB;
    ushort *oA, *oB;
};

__global__ __launch_bounds__(256) void gather64k(G64Args a) {
    const int side = blockIdx.x >= GBLK;
    const int bx = blockIdx.x - side * GBLK;
    const ushort* __restrict__ x = side ? a.xB : a.xA;
    const int* __restrict__ rowptr = side ? a.rpB : a.rpA;
    const int* __restrict__ col = side ? a.colB : a.colA;
    ushort* __restrict__ out = side ? a.oB : a.oA;

    const int node = (bx * 256 + threadIdx.x) >> 6;
    const int l = threadIdx.x & 63;
    if (node >= NN) return;
    const int beg = rowptr[node], end = rowptr[node + 1];
    const int cg = (l & 31) * 2;    // 2-col group (4B)
    const int half = l >> 5;

    float a0 = 0.f, a1 = 0.f;
    int e = beg;
    for (; e + 3 < end; e += 4) {
        const int s0 = col[e + half], s1 = col[e + 2 + half];
        const unsigned int va = *(const unsigned int*)&x[(size_t)s0 * 64 + cg];
        const unsigned int vb = *(const unsigned int*)&x[(size_t)s1 * 64 + cg];
        a0 += bf2f(va & 0xffffu) + bf2f(vb & 0xffffu);
        a1 += bf2f(va >> 16) + bf2f(vb >> 16);
    }
    for (; e < end; e += 2) {
        const int eh = e + half;
        if (eh < end) {
            const unsigned int v = *(const unsigned int*)&x[(size_t)col[eh] * 64 + cg];
            a0 += bf2f(v & 0xffffu);
            a1 += bf2f(v >> 16);
        }
    }
    a0 += __shfl_xor(a0, 32);
    a1 += __shfl_xor(a1, 32);
    if (l < 32) {
        const unsigned int u0 = *(const unsigned int*)&x[(size_t)node * 64 + cg];
        a0 += bf2f(u0 & 0xffffu);
        a1 += bf2f(u0 >> 16);
        *(unsigned int*)&out[(size_t)node * 64 + cg] = f2b(a0) | (f2b(a1) << 16);
    }
}

// ---------------------------------------------------------------- post-GEMM gather (F=128, pure adds)
// one node per wave; lanes 0-31 edge e, 32-63 edge e+1; each lane uint2 (4 cols, 8B)
struct GPostArgs {
    const ushort *yA, *yB;
    const int *rpA, *rpB, *colA, *colB;
    ushort *rA, *rB;
};

__global__ __launch_bounds__(256) void gather_post(GPostArgs a) {
    const int side = blockIdx.x >= GBLK;
    const int bx = blockIdx.x - side * GBLK;
    const ushort* __restrict__ y = side ? a.yB : a.yA;
    const int* __restrict__ rowptr = side ? a.rpB : a.rpA;
    const int* __restrict__ col = side ? a.colB : a.colA;
    ushort* __restrict__ r = side ? a.rB : a.rA;

    const int node = (bx * 256 + threadIdx.x) >> 6;
    const int l = threadIdx.x & 63;
    if (node >= NN) return;
    const int beg = rowptr[node], end = rowptr[node + 1];
    const int cg = (l & 31) * 4;    // 4-col group (8B)
    const int half = l >> 5;

    float a0 = 0.f, a1 = 0.f, a2 = 0.f, a3 = 0.f;
    int e = beg;
    for (; e + 3 < end; e += 4) {
        const int s0 = col[e + half], s1 = col[e + 2 + half];
        const uint2 va = *(const uint2*)&y[(size_t)s0 * 128 + cg];
        const uint2 vb = *(const uint2*)&y[(size_t)s1 * 128 + cg];
        a0 += bf2f(va.x & 0xffffu) + bf2f(vb.x & 0xffffu);
        a1 += bf2f(va.x >> 16) + bf2f(vb.x >> 16);
        a2 += bf2f(va.y & 0xffffu) + bf2f(vb.y & 0xffffu);
        a3 += bf2f(va.y >> 16) + bf2f(vb.y >> 16);
    }
    for (; e < end; e += 2) {
        const int eh = e + half;
        if (eh < end) {
            const uint2 v = *(const uint2*)&y[(size_t)col[eh] * 128 + cg];
            a0 += bf2f(v.x & 0xffffu);
            a1 += bf2f(v.x >> 16);
            a2 += bf2f(v.y & 0xffffu);
            a3 += bf2f(v.y >> 16);
        }
    }
    a0 += __shfl_xor(a0, 32);
    a1 += __shfl_xor(a1, 32);
    a2 += __shfl_xor(a2, 32);
    a3 += __shfl_xor(a3, 32);
    if (l < 32) {
        const uint2 u0 = *(const uint2*)&y[(size_t)node * 128 + cg];
        a0 += bf2f(u0.x & 0xffffu);
        a1 += bf2f(u0.x >> 16);
        a2 += bf2f(u0.y & 0xffffu);
        a3 += bf2f(u0.y >> 16);
        uint2 pk;
        pk.x = f2b(a0) | (f2b(a1) << 16);
        pk.y = f2b(a2) | (f2b(a3) << 16);
        *(uint2*)&r[(size_t)node * 128 + cg] = pk;
    }
}

// ---------------------------------------------------------------- streaming BN stats (sum, sumsq) over bf16 [NN][128]
__global__ __launch_bounds__(256) void stats_pass(const ushort* __restrict__ hA,
                                                  const ushort* __restrict__ hB,
                                                  float* __restrict__ stA,
                                                  float* __restrict__ stB) {
    const int side = blockIdx.x >= NSB;
    const int bx = blockIdx.x - side * NSB;
    const ushort* __restrict__ h = side ? hB : hA;
    float* __restrict__ st = side ? stB : stA;
    const int t = threadIdx.x;
    const int c2 = (t & 63) * 2;
    const int rsub = t >> 6;            // 0..3
    const int rbeg = bx * 128;
    const int rend = min(rbeg + 128, NN);
    float s0 = 0.f, s1 = 0.f, q0 = 0.f, q1 = 0.f;
    for (int rr = rbeg + rsub; rr < rend; rr += 4) {
        const unsigned int u = *(const unsigned int*)&h[(size_t)rr * 128 + c2];
        const float e0 = bf2f(u & 0xffffu), e1 = bf2f(u >> 16);
        s0 += e0; s1 += e1;
        q0 = fmaf(e0, e0, q0); q1 = fmaf(e1, e1, q1);
    }
    __shared__ float red[512];
    red[rsub * 128 + c2] = s0; red[rsub * 128 + c2 + 1] = s1;
    __syncthreads();
    if (t < 128) {
        const float v = red[t] + red[128 + t] + red[256 + t] + red[384 + t];
        unsafeAtomicAdd(&st[t], v);
    }
    __syncthreads();
    red[rsub * 128 + c2] = q0; red[rsub * 128 + c2 + 1] = q1;
    __syncthreads();
    if (t < 128) {
        const float v = red[t] + red[128 + t] + red[256 + t] + red[384 + t];
        unsafeAtomicAdd(&st[128 + t], v);
    }
}

// ---------------------------------------------------------------- MFMA GEMM: C = f(M) @ W (bf16)
// f = APPLY_BN ? relu(bn(v)) (coefs from raw stats, applied during M staging) : identity.
// STATS: fused column stats of rounded C in epilogue (layer 1 only). No bias (zeros + BN shift-invariance).
struct GemmArgs {
    const ushort *mA, *mB;
    const ushort *WT;              // [128][FIN] bf16, transposed
    ushort *cA, *cB;
    float *stA, *stB;              // STATS: out; APPLY_BN: in (raw sums of M)
    const float *gamma, *beta;     // APPLY_BN only
};

template<int FIN, bool APPLY_BN, bool STATS>
__global__ __launch_bounds__(256) void gemm_mfma(GemmArgs g) {
    constexpr int FP = FIN + 8;          // padded LDS stride (bf16 units)
    constexpr int CPR = FIN / 8;         // 16B chunks per row
    const int side = blockIdx.x >= NBG;
    const int bx = blockIdx.x - side * NBG;
    const ushort* __restrict__ M = side ? g.mB : g.mA;
    ushort* __restrict__ C = side ? g.cB : g.cA;
    float* __restrict__ stats = side ? g.stB : g.stA;

    __shared__ ushort sh[64 * 136 + 128 * FP];
    ushort* Ml = sh;                     // M tile (stride FP); later C tile (stride 136)
    ushort* Wl = sh + 64 * 136;          // WT tile (stride FP); later stats red (fp32)

    const int t = threadIdx.x;
    const int w = t >> 6;                // wave 0..3
    const int l = t & 63;
    const int lr = l & 15;
    const int lg = l >> 4;
    const int r0 = bx * 64;

    // per-thread BN coefs for its 8 staging columns (k-dim = prev layer's feature dim)
    float ca[8], cb[8];
    if (APPLY_BN) {
        const float* __restrict__ st = stats;
        const int cc = (t % CPR) * 8;
        const float inv_n = 1.f / (float)NN;
        #pragma unroll
        for (int j = 0; j < 8; ++j) {
            const int c = cc + j;
            const float mu = st[c] * inv_n;
            const float var = st[128 + c] * inv_n - mu * mu;
            ca[j] = g.gamma[c] * rsqrtf(var + BN_EPS);
            cb[j] = fmaf(-mu, ca[j], g.beta[c]);
        }
    }

    // ---- stage f(M) (64 x FIN)
    #pragma unroll
    for (int it = 0; it < (64 * CPR) / 256; ++it) {
        const int cid = it * 256 + t;
        const int row = cid / CPR, cc = (cid % CPR) * 8;
        const int r = r0 + row;
        uint4 v = make_uint4(0u, 0u, 0u, 0u);
        if (r < NN) v = *(const uint4*)&M[(size_t)r * FIN + cc];
        if (APPLY_BN) {
            unsigned int vv[4] = {v.x, v.y, v.z, v.w};
            #pragma unroll
            for (int q2 = 0; q2 < 4; ++q2) {
                float e0 = bf2f(vv[q2] & 0xffffu), e1 = bf2f(vv[q2] >> 16);
                e0 = fmaxf(fmaf(e0, ca[2 * q2], cb[2 * q2]), 0.f);
                e1 = fmaxf(fmaf(e1, ca[2 * q2 + 1], cb[2 * q2 + 1]), 0.f);
                vv[q2] = f2b(e0) | (f2b(e1) << 16);
            }
            v = make_uint4(vv[0], vv[1], vv[2], vv[3]);
        }
        *(uint4*)&Ml[row * FP + cc] = v;
    }
    // ---- stage WT (128 x FIN)
    #pragma unroll
    for (int it = 0; it < (128 * CPR) / 256; ++it) {
        const int cid = it * 256 + t;
        const int c = cid / CPR, kk = (cid % CPR) * 8;
        *(uint4*)&Wl[c * FP + kk] = *(const uint4*)&g.WT[c * FIN + kk];
    }
    __syncthreads();

    f32x4 acc[4][2];
    #pragma unroll
    for (int fi = 0; fi < 4; ++fi)
        #pragma unroll
        for (int fj = 0; fj < 2; ++fj)
            acc[fi][fj] = (f32x4){0.f, 0.f, 0.f, 0.f};

    #pragma unroll
    for (int kc = 0; kc < FIN / 32; ++kc) {
        const int kb = kc * 32 + lg * 8;
        bf16x8 a[4], b[2];
        #pragma unroll
        for (int fi = 0; fi < 4; ++fi)
            a[fi] = *(const bf16x8*)&Ml[(fi * 16 + lr) * FP + kb];
        #pragma unroll
        for (int fj = 0; fj < 2; ++fj)
            b[fj] = *(const bf16x8*)&Wl[(w * 32 + fj * 16 + lr) * FP + kb];
        #pragma unroll
        for (int fi = 0; fi < 4; ++fi)
            #pragma unroll
            for (int fj = 0; fj < 2; ++fj)
                acc[fi][fj] = __builtin_amdgcn_mfma_f32_16x16x32_bf16(a[fi], b[fj], acc[fi][fj], 0, 0, 0);
    }
    __syncthreads();   // all LDS reads done; Ml/Wl reusable

    // ---- stage C tile (bf16) into Ml (stride 136); C/D layout: col=lane&15, row=(lane>>4)*4+j
    #pragma unroll
    for (int fi = 0; fi < 4; ++fi)
        #pragma unroll
        for (int fj = 0; fj < 2; ++fj)
            #pragma unroll
            for (int j = 0; j < 4; ++j) {
                const int row = fi * 16 + lg * 4 + j;
                const int c = w * 32 + fj * 16 + lr;
                Ml[row * 136 + c] = (ushort)f2b(acc[fi][fj][j]);
            }
    __syncthreads();

    // ---- epilogue: coalesced global store (+ BN partial stats for layer 1)
    const int ry = t >> 4, c0 = (t & 15) * 8;
    float sc[8], qc[8];
    if (STATS) {
        #pragma unroll
        for (int j = 0; j < 8; ++j) { sc[j] = 0.f; qc[j] = 0.f; }
    }
    #pragma unroll
    for (int i = 0; i < 4; ++i) {
        const int rr = ry * 4 + i;
        const int r = r0 + rr;
        if (r < NN) {
            const uint4 pk = *(const uint4*)&Ml[rr * 136 + c0];
            if (STATS) {
                const unsigned int uu[4] = {pk.x, pk.y, pk.z, pk.w};
                #pragma unroll
                for (int q2 = 0; q2 < 4; ++q2) {
                    const float e0 = bf2f(uu[q2] & 0xffffu);
                    const float e1 = bf2f(uu[q2] >> 16);
                    sc[2 * q2] += e0;       sc[2 * q2 + 1] += e1;
                    qc[2 * q2] = fmaf(e0, e0, qc[2 * q2]);
                    qc[2 * q2 + 1] = fmaf(e1, e1, qc[2 * q2 + 1]);
                }
            }
            *(uint4*)&C[(size_t)r * HID + c0] = pk;
        }
    }
    if (STATS) {
        float* red = (float*)Wl;             // 2048 floats
        #pragma unroll
        for (int j = 0; j < 8; ++j) red[ry * 128 + c0 + j] = sc[j];
        __syncthreads();
        if (t < 128) {
            float a = 0.f;
            #pragma unroll
            for (int k = 0; k < 16; ++k) a += red[k * 128 + t];
            unsafeAtomicAdd(&stats[t], a);
        }
        __syncthreads();
        #pragma unroll
        for (int j = 0; j < 8; ++j) red[ry * 128 + c0 + j] = qc[j];
        __syncthreads();
        if (t < 128) {
            float a = 0.f;
            #pragma unroll
            for (int k = 0; k < 16; ++k) a += red[k * 128 + t];
            unsafeAtomicAdd(&stats[128 + t], a);
        }
    }
}

// ---------------------------------------------------------------- pool, both sides, BN3+ReLU fused
struct PoolArgs {
    const ushort *hA, *hB;
    const void *btA, *btB;
    const float *stA, *stB;
    const float *gamma, *beta;
    float *pooled, *cnt;
    const int* flag;
};

__global__ __launch_bounds__(128) void pool16(PoolArgs p) {
    const int side = blockIdx.x >= NBG;
    const int bx = blockIdx.x - side * NBG;
    const ushort* __restrict__ h = side ? p.hB : p.hA;
    const void* __restrict__ batch = side ? p.btB : p.btA;
    const float* __restrict__ st = side ? p.stB : p.stA;
    float* pooled = p.pooled + side * NG * HID;
    float* cnt = p.cnt + side * NG;
    const bool is64 = (*p.flag != 0);
    const int c = threadIdx.x;

    const float inv_n = 1.f / (float)NN;
    const float mu = st[c] * inv_n;
    const float var = st[128 + c] * inv_n - mu * mu;
    const float ca = p.gamma[c] * rsqrtf(var + BN_EPS);
    const float cb = fmaf(-mu, ca, p.beta[c]);

    const int rbeg = bx * 64;
    if (rbeg >= NN) return;
    const int rend = min(rbeg + 64, NN);
    const int g0 = load_idx(batch, rbeg, is64);
    const int g1 = load_idx(batch, rend - 1, is64);
    if (g0 == g1) {
        float acc = 0.f;
        #pragma unroll 8
        for (int r = rbeg; r < rend; ++r)
            acc += fmaxf(fmaf(bf2f(h[r * HID + c]), ca, cb), 0.f);
        unsafeAtomicAdd(&pooled[g0 * HID + c], acc);
        if (c == 0) unsafeAtomicAdd(&cnt[g0], (float)(rend - rbeg));
        return;
    }
    int gprev = g0;
    float acc = 0.f; int run = 0;
    for (int r = rbeg; r < rend; ++r) {
        const int g = load_idx(batch, r, is64);
        if (g != gprev) {
            unsafeAtomicAdd(&pooled[gprev * HID + c], acc);
            if (c == 0) unsafeAtomicAdd(&cnt[gprev], (float)run);
            acc = 0.f; run = 0; gprev = g;
        }
        acc += fmaxf(fmaf(bf2f(h[r * HID + c]), ca, cb), 0.f);
        ++run;
    }
    unsafeAtomicAdd(&pooled[gprev * HID + c], acc);
    if (c == 0) unsafeAtomicAdd(&cnt[gprev], (float)run);
}

__global__ __launch_bounds__(64) void pool_proj(const float* __restrict__ pooled,
                                                const float* __restrict__ cnt,
                                                const float* __restrict__ Wf,
                                                const float* __restrict__ bf,
                                                float* __restrict__ v) {
    const int side = blockIdx.x >= NG;
    const int g = blockIdx.x - side * NG;
    const int c = threadIdx.x;  // 64
    const float* pp = pooled + side * NG * HID + g * HID;
    const float inv = 1.f / fmaxf(cnt[side * NG + g], 1.f);
    float acc = 0.f;
    for (int k = 0; k < HID; ++k) acc = fmaf(pp[k], Wf[k * EMB + c], acc);
    v[side * NG * EMB + g * EMB + c] = fmaf(acc, inv, bf[c]);
}

// ---------------------------------------------------------------- classifier head
__global__ __launch_bounds__(256) void classifier(const float* __restrict__ v1,
                                                  const float* __restrict__ v2,
                                                  const float* __restrict__ Wc1,
                                                  const float* __restrict__ bc1,
                                                  const float* __restrict__ Wc2,
                                                  const float* __restrict__ bc2,
                                                  float* __restrict__ out) {
    const int g = threadIdx.x;
    if (g >= NG) return;
    float d[EMB];
    #pragma unroll
    for (int c = 0; c < EMB; ++c) d[c] = fabsf(v1[g * EMB + c] - v2[g * EMB + c]);
    float o = bc2[0];
    for (int j = 0; j < 32; ++j) {
        float h = bc1[j];
        #pragma unroll
        for (int c = 0; c < EMB; ++c) h = fmaf(d[c], Wc1[c * 32 + j], h);
        h = fmaxf(h, 0.f);
        o = fmaf(h, Wc2[j], o);
    }
    out[g] = 1.f / (1.f + expf(-o));
}

// ---------------------------------------------------------------- launch
extern "C" void kernel_launch(void* const* d_in, const int* in_sizes, int n_in,
                              void* d_out, int out_size, void* d_ws, size_t ws_size,
                              hipStream_t stream) {
    const float* x1 = (const float*)d_in[0];
    const float* x2 = (const float*)d_in[1];
    const void* ei1 = d_in[2];
    const void* ei2 = d_in[3];
    const void* bt1 = d_in[4];
    const void* bt2 = d_in[5];
    const float* W[3]  = {(const float*)d_in[6],  (const float*)d_in[10], (const float*)d_in[14]};
    const float* gg[3] = {(const float*)d_in[8],  (const float*)d_in[12], (const float*)d_in[16]};
    const float* be[3] = {(const float*)d_in[9],  (const float*)d_in[13], (const float*)d_in[17]};
    const float* Wf  = (const float*)d_in[18];
    const float* bfv = (const float*)d_in[19];
    const float* Wc1 = (const float*)d_in[20];
    const float* bc1 = (const float*)d_in[21];
    const float* Wc2 = (const float*)d_in[22];
    const float* bc2 = (const float*)d_in[23];

    // ---- workspace carve-up (256B-aligned)
    char* cur = (char*)d_ws;
    auto alloc = [&](size_t bytes) -> void* {
        void* p = cur;
        cur += (bytes + 255) & ~(size_t)255;
        return p;
    };
    ushort* P0 = (ushort*)alloc((size_t)NN * HID * 2);   // side0: x16 / r1 / r2 / r3
    ushort* P1 = (ushort*)alloc((size_t)NN * HID * 2);
    ushort* Q0 = (ushort*)alloc((size_t)NN * HID * 2);   // side0: agg1 / y2 / y3
    ushort* Q1 = (ushort*)alloc((size_t)NN * HID * 2);
    int* deg2   = (int*)alloc((size_t)2 * NN * 4);
    int* rpA    = (int*)alloc((size_t)(NN + 1) * 4);
    int* rpB    = (int*)alloc((size_t)(NN + 1) * 4);
    int* curA   = (int*)alloc((size_t)NN * 4);
    int* curB   = (int*)alloc((size_t)NN * 4);
    int* bsum   = (int*)alloc(256 * 4);
    int* boff   = (int*)alloc(256 * 4);
    int* colA   = (int*)alloc((size_t)NE * 4);
    int* colB   = (int*)alloc((size_t)NE * 4);
    int* flag   = (int*)alloc(64);
    ushort* WT1 = (ushort*)alloc(128 * 64 * 2);
    ushort* WT2 = (ushort*)alloc(128 * 128 * 2);
    ushort* WT3 = (ushort*)alloc(128 * 128 * 2);
    float* zreg = (float*)alloc((size_t)(6 * 256 + 2 * NG * HID + 2 * NG) * 4);
    float* stats  = zreg;                         // 6 x 256 (sum[128], sumsq[128])
    float* pooled = stats + 6 * 256;              // 2 x G x 128
    float* cnt    = pooled + 2 * NG * HID;        // 2 x G
    float* vv     = (float*)alloc((size_t)2 * NG * EMB * 4);
    int* degA = deg2, *degB = deg2 + NN;

    hipMemsetAsync(deg2, 0, (size_t)2 * NN * 4, stream);
    hipMemsetAsync(zreg, 0, (size_t)(6 * 256 + 2 * NG * HID + 2 * NG) * 4, stream);
    detect_i64_kernel<<<1, 64, 0, stream>>>(ei1, flag);
    convert_x<<<(2 * NN * 16) / 256, 256, 0, stream>>>(x1, x2, P0, P1);
    prep_weights<<<160, 256, 0, stream>>>(W[0], W[1], W[2], WT1, WT2, WT3);

    // ---- CSR build (both sides fused; XCD-partitioned hist + fill)
    csr_hist_part<<<8 * 2 * NCH, 256, 0, stream>>>(ei1, ei2, degA, degB, flag);
    scan_block_sums2<<<2 * SNB, 256, 0, stream>>>(degA, degB, bsum);
    scan_bsums2<<<2, 128, 0, stream>>>(bsum, boff, rpA, rpB);
    scan_fill2<<<2 * SNB, 256, 0, stream>>>(degA, degB, boff, rpA, rpB, curA, curB);
    csr_fill_part<<<8 * 2 * NCH, 256, 0, stream>>>(ei1, ei2, curA, curB, colA, colB, flag);

    float* st1A = stats + 0 * 256, *st1B = stats + 1 * 256;   // stats of r1 (BN1)
    float* st2A = stats + 2 * 256, *st2B = stats + 3 * 256;   // stats of r2 (BN2)
    float* st3A = stats + 4 * 256, *st3B = stats + 5 * 256;   // stats of r3 (BN3)

    // ---- layer 1: agg1 = (1+A)x16  P->Q ;  r1 = agg1 @ W1 -> P (+stats1)
    {
        G64Args a = {P0, P1, rpA, rpB, colA, colB, Q0, Q1};
        gather64k<<<2 * GBLK, 256, 0, stream>>>(a);
        GemmArgs g = {Q0, Q1, WT1, P0, P1, st1A, st1B, nullptr, nullptr};
        gemm_mfma<64, false, true><<<2 * NBG, 256, 0, stream>>>(g);
    }
    // ---- layer 2: y2 = f1(r1) @ W2  P->Q ;  r2 = (1+A)y2 -> P ; stats2
    {
        GemmArgs g = {P0, P1, WT2, Q0, Q1, st1A, st1B, gg[0], be[0]};
        gemm_mfma<128, true, false><<<2 * NBG, 256, 0, stream>>>(g);
        GPostArgs a = {Q0, Q1, rpA, rpB, colA, colB, P0, P1};
        gather_post<<<2 * GBLK, 256, 0, stream>>>(a);
        stats_pass<<<2 * NSB, 256, 0, stream>>>(P0, P1, st2A, st2B);
    }
    // ---- layer 3: y3 = f2(r2) @ W3  P->Q ;  r3 = (1+A)y3 -> P ; stats3
    {
        GemmArgs g = {P0, P1, WT3, Q0, Q1, st2A, st2B, gg[1], be[1]};
        gemm_mfma<128, true, false><<<2 * NBG, 256, 0, stream>>>(g);
        GPostArgs a = {Q0, Q1, rpA, rpB, colA, colB, P0, P1};
        gather_post<<<2 * GBLK, 256, 0, stream>>>(a);
        stats_pass<<<2 * NSB, 256, 0, stream>>>(P0, P1, st3A, st3B);
    }
    // ---- pool (BN3+ReLU fused), projection, classifier
    {
        PoolArgs p = {P0, P1, bt1, bt2, st3A, st3B, gg[2], be[2], pooled, cnt, flag};
        pool16<<<2 * NBG, 128, 0, stream>>>(p);
    }
    pool_proj<<<2 * NG, 64, 0, stream>>>(pooled, cnt, Wf, bfv, vv);
    classifier<<<1, 256, 0, stream>>>(vv, vv + NG * EMB, Wc1, bc1, Wc2, bc2, (float*)d_out);
}

// Round 10
// 942.356 us; speedup vs baseline: 1.0494x; 1.0494x over previous
//
#include <hip/hip_runtime.h>
#include <hip/hip_bf16.h>
#include <math.h>

#define NN 100000
#define NE 1280000
#define NG 256
#define HID 128
#define EMB 64
#define BN_EPS 1e-5f
#define SB 1024
#define SNB ((NN + SB - 1) / SB)   // 98
#define NBG 1563                   // gemm/pool blocks per side (64 rows/block)
#define GBLK 25000                 // gather blocks per side (4 nodes/block)
#define NSB 782                    // stats blocks per side (128 rows/block)
#define PART ((NN + 7) / 8)        // 12500 dsts per XCD partition
#define FCH 2048                   // edges per fill chunk
#define NCH (NE / FCH)             // 625

typedef __attribute__((ext_vector_type(8))) __bf16 bf16x8;
typedef __attribute__((ext_vector_type(4))) float f32x4;

// ---------------------------------------------------------------- bf16 helpers (manual, RNE)
__device__ __forceinline__ float bf2f(unsigned int u) { return __uint_as_float(u << 16); }
__device__ __forceinline__ unsigned int f2b(float f) {
    unsigned int u = __float_as_uint(f);
    return (u + 0x7fffu + ((u >> 16) & 1u)) >> 16;
}

// ---------------------------------------------------------------- utilities
__global__ void detect_i64_kernel(const void* __restrict__ ei, int* __restrict__ flag) {
    if (threadIdx.x == 0 && blockIdx.x == 0) {
        const unsigned long long* p = (const unsigned long long*)ei;
        int is64 = 1;
        #pragma unroll
        for (int i = 0; i < 16; ++i)
            if (p[i] >= (1ull << 32)) is64 = 0;
        *flag = is64;
    }
}

__device__ __forceinline__ int load_idx(const void* p, int i, bool is64) {
    return is64 ? (int)((const long long*)p)[i] : ((const int*)p)[i];
}

// ---------------------------------------------------------------- x -> bf16 (both sides)
__global__ __launch_bounds__(256) void convert_x(const float* __restrict__ x1,
                                                 const float* __restrict__ x2,
                                                 ushort* __restrict__ o1,
                                                 ushort* __restrict__ o2) {
    const int per = NN * 16;
    const int i = blockIdx.x * 256 + threadIdx.x;
    const int side = i >= per;
    const int j = i - side * per;
    const float4 v = ((const float4*)(side ? x2 : x1))[j];
    ushort4 o;
    o.x = (ushort)f2b(v.x); o.y = (ushort)f2b(v.y);
    o.z = (ushort)f2b(v.z); o.w = (ushort)f2b(v.w);
    ((ushort4*)(side ? o2 : o1))[j] = o;
}

// ---------------------------------------------------------------- weights -> bf16 transposed WT[c][k]
__global__ __launch_bounds__(256) void prep_weights(const float* __restrict__ W1,
                                                    const float* __restrict__ W2,
                                                    const float* __restrict__ W3,
                                                    ushort* __restrict__ T1,
                                                    ushort* __restrict__ T2,
                                                    ushort* __restrict__ T3) {
    const int i = blockIdx.x * 256 + threadIdx.x;   // 40960 total
    if (i < 8192) {                 // W1: [64][128]
        const int k = i >> 7, c = i & 127;
        T1[c * 64 + k] = (ushort)f2b(W1[i]);
    } else if (i < 24576) {         // W2: [128][128]
        const int j = i - 8192, k = j >> 7, c = j & 127;
        T2[c * 128 + k] = (ushort)f2b(W2[j]);
    } else if (i < 40960) {         // W3
        const int j = i - 24576, k = j >> 7, c = j & 127;
        T3[c * 128 + k] = (ushort)f2b(W3[j]);
    }
}

// ---------------------------------------------------------------- CSR build
// hist: edge-parallel (R5-R8 proven; partitioned variant regressed in R9)
__global__ __launch_bounds__(256) void csr_hist2(const void* __restrict__ e1,
                                                 const void* __restrict__ e2,
                                                 int* __restrict__ degA,
                                                 int* __restrict__ degB,
                                                 const int* __restrict__ flag) {
    const bool is64 = (*flag != 0);
    const int i = blockIdx.x * 256 + threadIdx.x;
    if (i < 2 * NE) {
        const int side = i >= NE;
        const int j = i - side * NE;
        atomicAdd(&(side ? degB : degA)[load_idx(side ? e2 : e1, NE + j, is64)], 1);
    }
}

__global__ __launch_bounds__(256) void scan_block_sums2(const int* __restrict__ degA,
                                                        const int* __restrict__ degB,
                                                        int* __restrict__ bsum) {
    const int side = blockIdx.x >= SNB;
    const int bx = blockIdx.x - side * SNB;
    const int* deg = side ? degB : degA;
    const int t = threadIdx.x;
    const int base = bx * SB + t * 4;
    int s = 0;
    #pragma unroll
    for (int k = 0; k < 4; ++k) {
        const int i = base + k;
        if (i < NN) s += deg[i];
    }
    __shared__ int red[256];
    red[t] = s;
    __syncthreads();
    for (int off = 128; off > 0; off >>= 1) {
        if (t < off) red[t] += red[t + off];
        __syncthreads();
    }
    if (t == 0) bsum[side * 128 + bx] = red[0];
}

__global__ __launch_bounds__(128) void scan_bsums2(const int* __restrict__ bsum,
                                                   int* __restrict__ boff,
                                                   int* __restrict__ rpA,
                                                   int* __restrict__ rpB) {
    const int side = blockIdx.x;
    __shared__ int s[128];
    const int t = threadIdx.x;
    s[t] = (t < SNB) ? bsum[side * 128 + t] : 0;
    __syncthreads();
    for (int off = 1; off < 128; off <<= 1) {
        const int v = (t >= off) ? s[t - off] : 0;
        __syncthreads();
        s[t] += v;
        __syncthreads();
    }
    boff[side * 128 + t] = (t == 0) ? 0 : s[t - 1];
    if (t == 0) (side ? rpB : rpA)[NN] = s[SNB - 1];
}

__global__ __launch_bounds__(256) void scan_fill2(const int* __restrict__ degA,
                                                  const int* __restrict__ degB,
                                                  const int* __restrict__ boff,
                                                  int* __restrict__ rpA,
                                                  int* __restrict__ rpB,
                                                  int* __restrict__ curA,
                                                  int* __restrict__ curB) {
    const int side = blockIdx.x >= SNB;
    const int bx = blockIdx.x - side * SNB;
    const int* deg = side ? degB : degA;
    int* rowptr = side ? rpB : rpA;
    int* cursor = side ? curB : curA;
    const int t = threadIdx.x;
    const int base = bx * SB + t * 4;
    int v[4], s = 0;
    #pragma unroll
    for (int k = 0; k < 4; ++k) {
        const int i = base + k;
        v[k] = (i < NN) ? deg[i] : 0;
        s += v[k];
    }
    __shared__ int red[256];
    red[t] = s;
    __syncthreads();
    for (int off = 1; off < 256; off <<= 1) {
        const int x = (t >= off) ? red[t - off] : 0;
        __syncthreads();
        red[t] += x;
        __syncthreads();
    }
    int run = boff[side * 128 + bx] + ((t == 0) ? 0 : red[t - 1]);
    #pragma unroll
    for (int k = 0; k < 4; ++k) {
        const int i = base + k;
        if (i < NN) {
            rowptr[i] = run;
            cursor[i] = run;
            run += v[k];
        }
    }
}

// fill, dst-partitioned so each col region is written by one XCD (proven: WRITE_SIZE 175->~20MB)
__global__ __launch_bounds__(256) void csr_fill_part(const void* __restrict__ e1,
                                                     const void* __restrict__ e2,
                                                     int* __restrict__ curA,
                                                     int* __restrict__ curB,
                                                     int* __restrict__ colA,
                                                     int* __restrict__ colB,
                                                     const int* __restrict__ flag) {
    const bool is64 = (*flag != 0);
    const int g = blockIdx.x & 7;
    const int q = blockIdx.x >> 3;
    const int side = q >= NCH;
    const int chunk = q - side * NCH;
    const void* __restrict__ e = side ? e2 : e1;
    int* __restrict__ cur = side ? curB : curA;
    int* __restrict__ col = side ? colB : colA;
    const int lo = g * PART;
    const int hi = min(lo + PART, NN);
    const int base = chunk * FCH;
    for (int i = base + threadIdx.x; i < base + FCH; i += 256) {
        const int d = load_idx(e, NE + i, is64);
        if (d >= lo && d < hi) {
            const int pos = atomicAdd(&cur[d], 1);
            col[pos] = load_idx(e, i, is64);
        }
    }
}

// ---------------------------------------------------------------- layer-1 gather (F=64, pure sum)
// R7 structure: 1 node/wave, lane = 1 col (2B scalar loads), 4 independent loads per iter
struct G64Args {
    const ushort *xA, *xB;
    const int *rpA, *rpB, *colA, *colB;
    ushort *oA, *oB;
};

__global__ __launch_bounds__(256) void gather64k(G64Args a) {
    const int side = blockIdx.x >= GBLK;
    const int bx = blockIdx.x - side * GBLK;
    const ushort* __restrict__ x = side ? a.xB : a.xA;
    const int* __restrict__ rowptr = side ? a.rpB : a.rpA;
    const int* __restrict__ col = side ? a.colB : a.colA;
    ushort* __restrict__ out = side ? a.oB : a.oA;

    const int node = (bx * 256 + threadIdx.x) >> 6;
    const int lane = threadIdx.x & 63;
    if (node >= NN) return;
    const int beg = rowptr[node], end = rowptr[node + 1];
    float acc = bf2f(x[(size_t)node * 64 + lane]);
    int e = beg;
    for (; e + 3 < end; e += 4) {
        const int s0 = col[e], s1 = col[e + 1], s2 = col[e + 2], s3 = col[e + 3];
        acc += bf2f(x[(size_t)s0 * 64 + lane]) + bf2f(x[(size_t)s1 * 64 + lane])
             + bf2f(x[(size_t)s2 * 64 + lane]) + bf2f(x[(size_t)s3 * 64 + lane]);
    }
    for (; e < end; ++e) acc += bf2f(x[(size_t)col[e] * 64 + lane]);
    out[(size_t)node * 64 + lane] = (ushort)f2b(acc);
}

// ---------------------------------------------------------------- post-GEMM gather (F=128, pure adds)
// R7 structure: 1 node/wave, lane = 2 cols (4B loads), 4 independent loads per unrolled iter
struct GPostArgs {
    const ushort *yA, *yB;
    const int *rpA, *rpB, *colA, *colB;
    ushort *rA, *rB;
};

__global__ __launch_bounds__(256) void gather_post(GPostArgs a) {
    const int side = blockIdx.x >= GBLK;
    const int bx = blockIdx.x - side * GBLK;
    const ushort* __restrict__ y = side ? a.yB : a.yA;
    const int* __restrict__ rowptr = side ? a.rpB : a.rpA;
    const int* __restrict__ col = side ? a.colB : a.colA;
    ushort* __restrict__ r = side ? a.rB : a.rA;

    const int node = (bx * 256 + threadIdx.x) >> 6;
    const int lane = threadIdx.x & 63;
    if (node >= NN) return;
    const int beg = rowptr[node], end = rowptr[node + 1];
    const int c2 = lane * 2;

    const unsigned int u0 = *(const unsigned int*)&y[(size_t)node * 128 + c2];
    float ax = bf2f(u0 & 0xffffu), ay = bf2f(u0 >> 16);
    int e = beg;
    for (; e + 3 < end; e += 4) {
        const int s0 = col[e], s1 = col[e + 1], s2 = col[e + 2], s3 = col[e + 3];
        const unsigned int ua = *(const unsigned int*)&y[(size_t)s0 * 128 + c2];
        const unsigned int ub = *(const unsigned int*)&y[(size_t)s1 * 128 + c2];
        const unsigned int uc = *(const unsigned int*)&y[(size_t)s2 * 128 + c2];
        const unsigned int ud = *(const unsigned int*)&y[(size_t)s3 * 128 + c2];
        ax += bf2f(ua & 0xffffu) + bf2f(ub & 0xffffu) + bf2f(uc & 0xffffu) + bf2f(ud & 0xffffu);
        ay += bf2f(ua >> 16) + bf2f(ub >> 16) + bf2f(uc >> 16) + bf2f(ud >> 16);
    }
    for (; e < end; ++e) {
        const unsigned int u = *(const unsigned int*)&y[(size_t)col[e] * 128 + c2];
        ax += bf2f(u & 0xffffu);
        ay += bf2f(u >> 16);
    }
    *(unsigned int*)&r[(size_t)node * 128 + c2] = f2b(ax) | (f2b(ay) << 16);
}

// ---------------------------------------------------------------- streaming BN stats (sum, sumsq) over bf16 [NN][128]
__global__ __launch_bounds__(256) void stats_pass(const ushort* __restrict__ hA,
                                                  const ushort* __restrict__ hB,
                                                  float* __restrict__ stA,
                                                  float* __restrict__ stB) {
    const int side = blockIdx.x >= NSB;
    const int bx = blockIdx.x - side * NSB;
    const ushort* __restrict__ h = side ? hB : hA;
    float* __restrict__ st = side ? stB : stA;
    const int t = threadIdx.x;
    const int c2 = (t & 63) * 2;
    const int rsub = t >> 6;            // 0..3
    const int rbeg = bx * 128;
    const int rend = min(rbeg + 128, NN);
    float s0 = 0.f, s1 = 0.f, q0 = 0.f, q1 = 0.f;
    for (int rr = rbeg + rsub; rr < rend; rr += 4) {
        const unsigned int u = *(const unsigned int*)&h[(size_t)rr * 128 + c2];
        const float e0 = bf2f(u & 0xffffu), e1 = bf2f(u >> 16);
        s0 += e0; s1 += e1;
        q0 = fmaf(e0, e0, q0); q1 = fmaf(e1, e1, q1);
    }
    __shared__ float red[512];
    red[rsub * 128 + c2] = s0; red[rsub * 128 + c2 + 1] = s1;
    __syncthreads();
    if (t < 128) {
        const float v = red[t] + red[128 + t] + red[256 + t] + red[384 + t];
        unsafeAtomicAdd(&st[t], v);
    }
    __syncthreads();
    red[rsub * 128 + c2] = q0; red[rsub * 128 + c2 + 1] = q1;
    __syncthreads();
    if (t < 128) {
        const float v = red[t] + red[128 + t] + red[256 + t] + red[384 + t];
        unsafeAtomicAdd(&st[128 + t], v);
    }
}

// ---------------------------------------------------------------- MFMA GEMM: C = f(M) @ W (bf16)
// f = APPLY_BN ? relu(bn(v)) (coefs from raw stats, applied during M staging) : identity.
// STATS: fused column stats of rounded C in epilogue (layer 1 only). No bias (zeros + BN shift-invariance).
struct GemmArgs {
    const ushort *mA, *mB;
    const ushort *WT;              // [128][FIN] bf16, transposed
    ushort *cA, *cB;
    float *stA, *stB;              // STATS: out; APPLY_BN: in (raw sums of M)
    const float *gamma, *beta;     // APPLY_BN only
};

template<int FIN, bool APPLY_BN, bool STATS>
__global__ __launch_bounds__(256) void gemm_mfma(GemmArgs g) {
    constexpr int FP = FIN + 8;          // padded LDS stride (bf16 units)
    constexpr int CPR = FIN / 8;         // 16B chunks per row
    const int side = blockIdx.x >= NBG;
    const int bx = blockIdx.x - side * NBG;
    const ushort* __restrict__ M = side ? g.mB : g.mA;
    ushort* __restrict__ C = side ? g.cB : g.cA;
    float* __restrict__ stats = side ? g.stB : g.stA;

    __shared__ ushort sh[64 * 136 + 128 * FP];
    ushort* Ml = sh;                     // M tile (stride FP); later C tile (stride 136)
    ushort* Wl = sh + 64 * 136;          // WT tile (stride FP); later stats red (fp32)

    const int t = threadIdx.x;
    const int w = t >> 6;                // wave 0..3
    const int l = t & 63;
    const int lr = l & 15;
    const int lg = l >> 4;
    const int r0 = bx * 64;

    // per-thread BN coefs for its 8 staging columns (k-dim = prev layer's feature dim)
    float ca[8], cb[8];
    if (APPLY_BN) {
        const float* __restrict__ st = stats;
        const int cc = (t % CPR) * 8;
        const float inv_n = 1.f / (float)NN;
        #pragma unroll
        for (int j = 0; j < 8; ++j) {
            const int c = cc + j;
            const float mu = st[c] * inv_n;
            const float var = st[128 + c] * inv_n - mu * mu;
            ca[j] = g.gamma[c] * rsqrtf(var + BN_EPS);
            cb[j] = fmaf(-mu, ca[j], g.beta[c]);
        }
    }

    // ---- stage f(M) (64 x FIN)
    #pragma unroll
    for (int it = 0; it < (64 * CPR) / 256; ++it) {
        const int cid = it * 256 + t;
        const int row = cid / CPR, cc = (cid % CPR) * 8;
        const int r = r0 + row;
        uint4 v = make_uint4(0u, 0u, 0u, 0u);
        if (r < NN) v = *(const uint4*)&M[(size_t)r * FIN + cc];
        if (APPLY_BN) {
            unsigned int vv[4] = {v.x, v.y, v.z, v.w};
            #pragma unroll
            for (int q2 = 0; q2 < 4; ++q2) {
                float e0 = bf2f(vv[q2] & 0xffffu), e1 = bf2f(vv[q2] >> 16);
                e0 = fmaxf(fmaf(e0, ca[2 * q2], cb[2 * q2]), 0.f);
                e1 = fmaxf(fmaf(e1, ca[2 * q2 + 1], cb[2 * q2 + 1]), 0.f);
                vv[q2] = f2b(e0) | (f2b(e1) << 16);
            }
            v = make_uint4(vv[0], vv[1], vv[2], vv[3]);
        }
        *(uint4*)&Ml[row * FP + cc] = v;
    }
    // ---- stage WT (128 x FIN)
    #pragma unroll
    for (int it = 0; it < (128 * CPR) / 256; ++it) {
        const int cid = it * 256 + t;
        const int c = cid / CPR, kk = (cid % CPR) * 8;
        *(uint4*)&Wl[c * FP + kk] = *(const uint4*)&g.WT[c * FIN + kk];
    }
    __syncthreads();

    f32x4 acc[4][2];
    #pragma unroll
    for (int fi = 0; fi < 4; ++fi)
        #pragma unroll
        for (int fj = 0; fj < 2; ++fj)
            acc[fi][fj] = (f32x4){0.f, 0.f, 0.f, 0.f};

    #pragma unroll
    for (int kc = 0; kc < FIN / 32; ++kc) {
        const int kb = kc * 32 + lg * 8;
        bf16x8 a[4], b[2];
        #pragma unroll
        for (int fi = 0; fi < 4; ++fi)
            a[fi] = *(const bf16x8*)&Ml[(fi * 16 + lr) * FP + kb];
        #pragma unroll
        for (int fj = 0; fj < 2; ++fj)
            b[fj] = *(const bf16x8*)&Wl[(w * 32 + fj * 16 + lr) * FP + kb];
        #pragma unroll
        for (int fi = 0; fi < 4; ++fi)
            #pragma unroll
            for (int fj = 0; fj < 2; ++fj)
                acc[fi][fj] = __builtin_amdgcn_mfma_f32_16x16x32_bf16(a[fi], b[fj], acc[fi][fj], 0, 0, 0);
    }
    __syncthreads();   // all LDS reads done; Ml/Wl reusable

    // ---- stage C tile (bf16) into Ml (stride 136); C/D layout: col=lane&15, row=(lane>>4)*4+j
    #pragma unroll
    for (int fi = 0; fi < 4; ++fi)
        #pragma unroll
        for (int fj = 0; fj < 2; ++fj)
            #pragma unroll
            for (int j = 0; j < 4; ++j) {
                const int row = fi * 16 + lg * 4 + j;
                const int c = w * 32 + fj * 16 + lr;
                Ml[row * 136 + c] = (ushort)f2b(acc[fi][fj][j]);
            }
    __syncthreads();

    // ---- epilogue: coalesced global store (+ BN partial stats for layer 1)
    const int ry = t >> 4, c0 = (t & 15) * 8;
    float sc[8], qc[8];
    if (STATS) {
        #pragma unroll
        for (int j = 0; j < 8; ++j) { sc[j] = 0.f; qc[j] = 0.f; }
    }
    #pragma unroll
    for (int i = 0; i < 4; ++i) {
        const int rr = ry * 4 + i;
        const int r = r0 + rr;
        if (r < NN) {
            const uint4 pk = *(const uint4*)&Ml[rr * 136 + c0];
            if (STATS) {
                const unsigned int uu[4] = {pk.x, pk.y, pk.z, pk.w};
                #pragma unroll
                for (int q2 = 0; q2 < 4; ++q2) {
                    const float e0 = bf2f(uu[q2] & 0xffffu);
                    const float e1 = bf2f(uu[q2] >> 16);
                    sc[2 * q2] += e0;       sc[2 * q2 + 1] += e1;
                    qc[2 * q2] = fmaf(e0, e0, qc[2 * q2]);
                    qc[2 * q2 + 1] = fmaf(e1, e1, qc[2 * q2 + 1]);
                }
            }
            *(uint4*)&C[(size_t)r * HID + c0] = pk;
        }
    }
    if (STATS) {
        float* red = (float*)Wl;             // 2048 floats
        #pragma unroll
        for (int j = 0; j < 8; ++j) red[ry * 128 + c0 + j] = sc[j];
        __syncthreads();
        if (t < 128) {
            float a = 0.f;
            #pragma unroll
            for (int k = 0; k < 16; ++k) a += red[k * 128 + t];
            unsafeAtomicAdd(&stats[t], a);
        }
        __syncthreads();
        #pragma unroll
        for (int j = 0; j < 8; ++j) red[ry * 128 + c0 + j] = qc[j];
        __syncthreads();
        if (t < 128) {
            float a = 0.f;
            #pragma unroll
            for (int k = 0; k < 16; ++k) a += red[k * 128 + t];
            unsafeAtomicAdd(&stats[128 + t], a);
        }
    }
}

// ---------------------------------------------------------------- pool, both sides, BN3+ReLU fused
struct PoolArgs {
    const ushort *hA, *hB;
    const void *btA, *btB;
    const float *stA, *stB;
    const float *gamma, *beta;
    float *pooled, *cnt;
    const int* flag;
};

__global__ __launch_bounds__(128) void pool16(PoolArgs p) {
    const int side = blockIdx.x >= NBG;
    const int bx = blockIdx.x - side * NBG;
    const ushort* __restrict__ h = side ? p.hB : p.hA;
    const void* __restrict__ batch = side ? p.btB : p.btA;
    const float* __restrict__ st = side ? p.stB : p.stA;
    float* pooled = p.pooled + side * NG * HID;
    float* cnt = p.cnt + side * NG;
    const bool is64 = (*p.flag != 0);
    const int c = threadIdx.x;

    const float inv_n = 1.f / (float)NN;
    const float mu = st[c] * inv_n;
    const float var = st[128 + c] * inv_n - mu * mu;
    const float ca = p.gamma[c] * rsqrtf(var + BN_EPS);
    const float cb = fmaf(-mu, ca, p.beta[c]);

    const int rbeg = bx * 64;
    if (rbeg >= NN) return;
    const int rend = min(rbeg + 64, NN);
    const int g0 = load_idx(batch, rbeg, is64);
    const int g1 = load_idx(batch, rend - 1, is64);
    if (g0 == g1) {
        float acc = 0.f;
        #pragma unroll 8
        for (int r = rbeg; r < rend; ++r)
            acc += fmaxf(fmaf(bf2f(h[r * HID + c]), ca, cb), 0.f);
        unsafeAtomicAdd(&pooled[g0 * HID + c], acc);
        if (c == 0) unsafeAtomicAdd(&cnt[g0], (float)(rend - rbeg));
        return;
    }
    int gprev = g0;
    float acc = 0.f; int run = 0;
    for (int r = rbeg; r < rend; ++r) {
        const int g = load_idx(batch, r, is64);
        if (g != gprev) {
            unsafeAtomicAdd(&pooled[gprev * HID + c], acc);
            if (c == 0) unsafeAtomicAdd(&cnt[gprev], (float)run);
            acc = 0.f; run = 0; gprev = g;
        }
        acc += fmaxf(fmaf(bf2f(h[r * HID + c]), ca, cb), 0.f);
        ++run;
    }
    unsafeAtomicAdd(&pooled[gprev * HID + c], acc);
    if (c == 0) unsafeAtomicAdd(&cnt[gprev], (float)run);
}

__global__ __launch_bounds__(64) void pool_proj(const float* __restrict__ pooled,
                                                const float* __restrict__ cnt,
                                                const float* __restrict__ Wf,
                                                const float* __restrict__ bf,
                                                float* __restrict__ v) {
    const int side = blockIdx.x >= NG;
    const int g = blockIdx.x - side * NG;
    const int c = threadIdx.x;  // 64
    const float* pp = pooled + side * NG * HID + g * HID;
    const float inv = 1.f / fmaxf(cnt[side * NG + g], 1.f);
    float acc = 0.f;
    for (int k = 0; k < HID; ++k) acc = fmaf(pp[k], Wf[k * EMB + c], acc);
    v[side * NG * EMB + g * EMB + c] = fmaf(acc, inv, bf[c]);
}

// ---------------------------------------------------------------- classifier head
__global__ __launch_bounds__(256) void classifier(const float* __restrict__ v1,
                                                  const float* __restrict__ v2,
                                                  const float* __restrict__ Wc1,
                                                  const float* __restrict__ bc1,
                                                  const float* __restrict__ Wc2,
                                                  const float* __restrict__ bc2,
                                                  float* __restrict__ out) {
    const int g = threadIdx.x;
    if (g >= NG) return;
    float d[EMB];
    #pragma unroll
    for (int c = 0; c < EMB; ++c) d[c] = fabsf(v1[g * EMB + c] - v2[g * EMB + c]);
    float o = bc2[0];
    for (int j = 0; j < 32; ++j) {
        float h = bc1[j];
        #pragma unroll
        for (int c = 0; c < EMB; ++c) h = fmaf(d[c], Wc1[c * 32 + j], h);
        h = fmaxf(h, 0.f);
        o = fmaf(h, Wc2[j], o);
    }
    out[g] = 1.f / (1.f + expf(-o));
}

// ---------------------------------------------------------------- launch
extern "C" void kernel_launch(void* const* d_in, const int* in_sizes, int n_in,
                              void* d_out, int out_size, void* d_ws, size_t ws_size,
                              hipStream_t stream) {
    const float* x1 = (const float*)d_in[0];
    const float* x2 = (const float*)d_in[1];
    const void* ei1 = d_in[2];
    const void* ei2 = d_in[3];
    const void* bt1 = d_in[4];
    const void* bt2 = d_in[5];
    const float* W[3]  = {(const float*)d_in[6],  (const float*)d_in[10], (const float*)d_in[14]};
    const float* gg[3] = {(const float*)d_in[8],  (const float*)d_in[12], (const float*)d_in[16]};
    const float* be[3] = {(const float*)d_in[9],  (const float*)d_in[13], (const float*)d_in[17]};
    const float* Wf  = (const float*)d_in[18];
    const float* bfv = (const float*)d_in[19];
    const float* Wc1 = (const float*)d_in[20];
    const float* bc1 = (const float*)d_in[21];
    const float* Wc2 = (const float*)d_in[22];
    const float* bc2 = (const float*)d_in[23];

    // ---- workspace carve-up (256B-aligned)
    char* cur = (char*)d_ws;
    auto alloc = [&](size_t bytes) -> void* {
        void* p = cur;
        cur += (bytes + 255) & ~(size_t)255;
        return p;
    };
    ushort* P0 = (ushort*)alloc((size_t)NN * HID * 2);   // side0: x16 / r1 / r2 / r3
    ushort* P1 = (ushort*)alloc((size_t)NN * HID * 2);
    ushort* Q0 = (ushort*)alloc((size_t)NN * HID * 2);   // side0: agg1 / y2 / y3
    ushort* Q1 = (ushort*)alloc((size_t)NN * HID * 2);
    int* deg2   = (int*)alloc((size_t)2 * NN * 4);
    int* rpA    = (int*)alloc((size_t)(NN + 1) * 4);
    int* rpB    = (int*)alloc((size_t)(NN + 1) * 4);
    int* curA   = (int*)alloc((size_t)NN * 4);
    int* curB   = (int*)alloc((size_t)NN * 4);
    int* bsum   = (int*)alloc(256 * 4);
    int* boff   = (int*)alloc(256 * 4);
    int* colA   = (int*)alloc((size_t)NE * 4);
    int* colB   = (int*)alloc((size_t)NE * 4);
    int* flag   = (int*)alloc(64);
    ushort* WT1 = (ushort*)alloc(128 * 64 * 2);
    ushort* WT2 = (ushort*)alloc(128 * 128 * 2);
    ushort* WT3 = (ushort*)alloc(128 * 128 * 2);
    float* zreg = (float*)alloc((size_t)(6 * 256 + 2 * NG * HID + 2 * NG) * 4);
    float* stats  = zreg;                         // 6 x 256 (sum[128], sumsq[128])
    float* pooled = stats + 6 * 256;              // 2 x G x 128
    float* cnt    = pooled + 2 * NG * HID;        // 2 x G
    float* vv     = (float*)alloc((size_t)2 * NG * EMB * 4);
    int* degA = deg2, *degB = deg2 + NN;

    hipMemsetAsync(deg2, 0, (size_t)2 * NN * 4, stream);
    hipMemsetAsync(zreg, 0, (size_t)(6 * 256 + 2 * NG * HID + 2 * NG) * 4, stream);
    detect_i64_kernel<<<1, 64, 0, stream>>>(ei1, flag);
    convert_x<<<(2 * NN * 16) / 256, 256, 0, stream>>>(x1, x2, P0, P1);
    prep_weights<<<160, 256, 0, stream>>>(W[0], W[1], W[2], WT1, WT2, WT3);

    // ---- CSR build (edge-parallel hist; XCD-partitioned fill)
    const int EB2 = (2 * NE + 255) / 256;
    csr_hist2<<<EB2, 256, 0, stream>>>(ei1, ei2, degA, degB, flag);
    scan_block_sums2<<<2 * SNB, 256, 0, stream>>>(degA, degB, bsum);
    scan_bsums2<<<2, 128, 0, stream>>>(bsum, boff, rpA, rpB);
    scan_fill2<<<2 * SNB, 256, 0, stream>>>(degA, degB, boff, rpA, rpB, curA, curB);
    csr_fill_part<<<8 * 2 * NCH, 256, 0, stream>>>(ei1, ei2, curA, curB, colA, colB, flag);

    float* st1A = stats + 0 * 256, *st1B = stats + 1 * 256;   // stats of r1 (BN1)
    float* st2A = stats + 2 * 256, *st2B = stats + 3 * 256;   // stats of r2 (BN2)
    float* st3A = stats + 4 * 256, *st3B = stats + 5 * 256;   // stats of r3 (BN3)

    // ---- layer 1: agg1 = (1+A)x16  P->Q ;  r1 = agg1 @ W1 -> P (+stats1)
    {
        G64Args a = {P0, P1, rpA, rpB, colA, colB, Q0, Q1};
        gather64k<<<2 * GBLK, 256, 0, stream>>>(a);
        GemmArgs g = {Q0, Q1, WT1, P0, P1, st1A, st1B, nullptr, nullptr};
        gemm_mfma<64, false, true><<<2 * NBG, 256, 0, stream>>>(g);
    }
    // ---- layer 2: y2 = f1(r1) @ W2  P->Q ;  r2 = (1+A)y2 -> P ; stats2
    {
        GemmArgs g = {P0, P1, WT2, Q0, Q1, st1A, st1B, gg[0], be[0]};
        gemm_mfma<128, true, false><<<2 * NBG, 256, 0, stream>>>(g);
        GPostArgs a = {Q0, Q1, rpA, rpB, colA, colB, P0, P1};
        gather_post<<<2 * GBLK, 256, 0, stream>>>(a);
        stats_pass<<<2 * NSB, 256, 0, stream>>>(P0, P1, st2A, st2B);
    }
    // ---- layer 3: y3 = f2(r2) @ W3  P->Q ;  r3 = (1+A)y3 -> P ; stats3
    {
        GemmArgs g = {P0, P1, WT3, Q0, Q1, st2A, st2B, gg[1], be[1]};
        gemm_mfma<128, true, false><<<2 * NBG, 256, 0, stream>>>(g);
        GPostArgs a = {Q0, Q1, rpA, rpB, colA, colB, P0, P1};
        gather_post<<<2 * GBLK, 256, 0, stream>>>(a);
        stats_pass<<<2 * NSB, 256, 0, stream>>>(P0, P1, st3A, st3B);
    }
    // ---- pool (BN3+ReLU fused), projection, classifier
    {
        PoolArgs p = {P0, P1, bt1, bt2, st3A, st3B, gg[2], be[2], pooled, cnt, flag};
        pool16<<<2 * NBG, 128, 0, stream>>>(p);
    }
    pool_proj<<<2 * NG, 64, 0, stream>>>(pooled, cnt, Wf, bfv, vv);
    classifier<<<1, 256, 0, stream>>>(vv, vv + NG * EMB, Wc1, bc1, Wc2, bc2, (float*)d_out);
}

// Round 11
// 901.605 us; speedup vs baseline: 1.0969x; 1.0452x over previous
//
#include <hip/hip_runtime.h>
#include <hip/hip_bf16.h>
#include <math.h>

#define NN 100000
#define NE 1280000
#define NG 256
#define HID 128
#define EMB 64
#define BN_EPS 1e-5f
#define SB 1024
#define SNB ((NN + SB - 1) / SB)   // 98
#define NBG 1563                   // gemm/pool blocks per side (64 rows/block)
#define GBLK 25000                 // gather blocks per side (4 nodes/block)
#define NSB 782                    // stats blocks per side (128 rows/block)
#define PART ((NN + 7) / 8)        // 12500 dsts per XCD partition
#define FCH 2048                   // edges per fill chunk
#define NCH (NE / FCH)             // 625

typedef __attribute__((ext_vector_type(8))) __bf16 bf16x8;
typedef __attribute__((ext_vector_type(4))) float f32x4;

// ---------------------------------------------------------------- bf16 helpers (manual, RNE)
__device__ __forceinline__ float bf2f(unsigned int u) { return __uint_as_float(u << 16); }
__device__ __forceinline__ unsigned int f2b(float f) {
    unsigned int u = __float_as_uint(f);
    return (u + 0x7fffu + ((u >> 16) & 1u)) >> 16;
}

// ---------------------------------------------------------------- utilities
__global__ void detect_i64_kernel(const void* __restrict__ ei, int* __restrict__ flag) {
    if (threadIdx.x == 0 && blockIdx.x == 0) {
        const unsigned long long* p = (const unsigned long long*)ei;
        int is64 = 1;
        #pragma unroll
        for (int i = 0; i < 16; ++i)
            if (p[i] >= (1ull << 32)) is64 = 0;
        *flag = is64;
    }
}

__device__ __forceinline__ int load_idx(const void* p, int i, bool is64) {
    return is64 ? (int)((const long long*)p)[i] : ((const int*)p)[i];
}

// ---------------------------------------------------------------- x -> bf16 (both sides)
__global__ __launch_bounds__(256) void convert_x(const float* __restrict__ x1,
                                                 const float* __restrict__ x2,
                                                 ushort* __restrict__ o1,
                                                 ushort* __restrict__ o2) {
    const int per = NN * 16;
    const int i = blockIdx.x * 256 + threadIdx.x;
    const int side = i >= per;
    const int j = i - side * per;
    const float4 v = ((const float4*)(side ? x2 : x1))[j];
    ushort4 o;
    o.x = (ushort)f2b(v.x); o.y = (ushort)f2b(v.y);
    o.z = (ushort)f2b(v.z); o.w = (ushort)f2b(v.w);
    ((ushort4*)(side ? o2 : o1))[j] = o;
}

// ---------------------------------------------------------------- weights -> bf16 transposed WT[c][k]
__global__ __launch_bounds__(256) void prep_weights(const float* __restrict__ W1,
                                                    const float* __restrict__ W2,
                                                    const float* __restrict__ W3,
                                                    ushort* __restrict__ T1,
                                                    ushort* __restrict__ T2,
                                                    ushort* __restrict__ T3) {
    const int i = blockIdx.x * 256 + threadIdx.x;   // 40960 total
    if (i < 8192) {                 // W1: [64][128]
        const int k = i >> 7, c = i & 127;
        T1[c * 64 + k] = (ushort)f2b(W1[i]);
    } else if (i < 24576) {         // W2: [128][128]
        const int j = i - 8192, k = j >> 7, c = j & 127;
        T2[c * 128 + k] = (ushort)f2b(W2[j]);
    } else if (i < 40960) {         // W3
        const int j = i - 24576, k = j >> 7, c = j & 127;
        T3[c * 128 + k] = (ushort)f2b(W3[j]);
    }
}

// ---------------------------------------------------------------- edges -> int32 (src,dst) + fused deg histogram
__global__ __launch_bounds__(256) void convert_edges(const void* __restrict__ e1,
                                                     const void* __restrict__ e2,
                                                     int* __restrict__ es1, int* __restrict__ ed1,
                                                     int* __restrict__ es2, int* __restrict__ ed2,
                                                     int* __restrict__ degA, int* __restrict__ degB,
                                                     const int* __restrict__ flag) {
    const bool is64 = (*flag != 0);
    const int i = blockIdx.x * 256 + threadIdx.x;
    if (i < 2 * NE) {
        const int side = i >= NE;
        const int j = i - side * NE;
        const void* e = side ? e2 : e1;
        const int s = load_idx(e, j, is64);
        const int d = load_idx(e, NE + j, is64);
        (side ? es2 : es1)[j] = s;
        (side ? ed2 : ed1)[j] = d;
        atomicAdd(&(side ? degB : degA)[d], 1);
    }
}

// ---------------------------------------------------------------- CSR scans
__global__ __launch_bounds__(256) void scan_block_sums2(const int* __restrict__ degA,
                                                        const int* __restrict__ degB,
                                                        int* __restrict__ bsum) {
    const int side = blockIdx.x >= SNB;
    const int bx = blockIdx.x - side * SNB;
    const int* deg = side ? degB : degA;
    const int t = threadIdx.x;
    const int base = bx * SB + t * 4;
    int s = 0;
    #pragma unroll
    for (int k = 0; k < 4; ++k) {
        const int i = base + k;
        if (i < NN) s += deg[i];
    }
    __shared__ int red[256];
    red[t] = s;
    __syncthreads();
    for (int off = 128; off > 0; off >>= 1) {
        if (t < off) red[t] += red[t + off];
        __syncthreads();
    }
    if (t == 0) bsum[side * 128 + bx] = red[0];
}

__global__ __launch_bounds__(128) void scan_bsums2(const int* __restrict__ bsum,
                                                   int* __restrict__ boff,
                                                   int* __restrict__ rpA,
                                                   int* __restrict__ rpB) {
    const int side = blockIdx.x;
    __shared__ int s[128];
    const int t = threadIdx.x;
    s[t] = (t < SNB) ? bsum[side * 128 + t] : 0;
    __syncthreads();
    for (int off = 1; off < 128; off <<= 1) {
        const int v = (t >= off) ? s[t - off] : 0;
        __syncthreads();
        s[t] += v;
        __syncthreads();
    }
    boff[side * 128 + t] = (t == 0) ? 0 : s[t - 1];
    if (t == 0) (side ? rpB : rpA)[NN] = s[SNB - 1];
}

__global__ __launch_bounds__(256) void scan_fill2(const int* __restrict__ degA,
                                                  const int* __restrict__ degB,
                                                  const int* __restrict__ boff,
                                                  int* __restrict__ rpA,
                                                  int* __restrict__ rpB,
                                                  int* __restrict__ curA,
                                                  int* __restrict__ curB) {
    const int side = blockIdx.x >= SNB;
    const int bx = blockIdx.x - side * SNB;
    const int* deg = side ? degB : degA;
    int* rowptr = side ? rpB : rpA;
    int* cursor = side ? curB : curA;
    const int t = threadIdx.x;
    const int base = bx * SB + t * 4;
    int v[4], s = 0;
    #pragma unroll
    for (int k = 0; k < 4; ++k) {
        const int i = base + k;
        v[k] = (i < NN) ? deg[i] : 0;
        s += v[k];
    }
    __shared__ int red[256];
    red[t] = s;
    __syncthreads();
    for (int off = 1; off < 256; off <<= 1) {
        const int x = (t >= off) ? red[t - off] : 0;
        __syncthreads();
        red[t] += x;
        __syncthreads();
    }
    int run = boff[side * 128 + bx] + ((t == 0) ? 0 : red[t - 1]);
    #pragma unroll
    for (int k = 0; k < 4; ++k) {
        const int i = base + k;
        if (i < NN) {
            rowptr[i] = run;
            cursor[i] = run;
            run += v[k];
        }
    }
}

// fill, dst-partitioned so each col region is written by one XCD (proven: kills write amplification)
__global__ __launch_bounds__(256) void csr_fill_part(const int* __restrict__ es1,
                                                     const int* __restrict__ ed1,
                                                     const int* __restrict__ es2,
                                                     const int* __restrict__ ed2,
                                                     int* __restrict__ curA,
                                                     int* __restrict__ curB,
                                                     int* __restrict__ colA,
                                                     int* __restrict__ colB) {
    const int g = blockIdx.x & 7;
    const int q = blockIdx.x >> 3;
    const int side = q >= NCH;
    const int chunk = q - side * NCH;
    const int* __restrict__ srcs = side ? es2 : es1;
    const int* __restrict__ dsts = side ? ed2 : ed1;
    int* __restrict__ cur = side ? curB : curA;
    int* __restrict__ col = side ? colB : colA;
    const int lo = g * PART;
    const int hi = min(lo + PART, NN);
    const int base = chunk * FCH;
    for (int i = base + threadIdx.x; i < base + FCH; i += 256) {
        const int d = dsts[i];
        if (d >= lo && d < hi) {
            const int pos = atomicAdd(&cur[d], 1);
            col[pos] = srcs[i];
        }
    }
}

// ---------------------------------------------------------------- layer-1 gather (F=64, pure sum)
// 1 node/wave, lane = 1 col (2B scalar loads); 8->4->1 unroll for MLP
struct G64Args {
    const ushort *xA, *xB;
    const int *rpA, *rpB, *colA, *colB;
    ushort *oA, *oB;
};

__global__ __launch_bounds__(256) void gather64k(G64Args a) {
    const int side = blockIdx.x >= GBLK;
    const int bx = blockIdx.x - side * GBLK;
    const ushort* __restrict__ x = side ? a.xB : a.xA;
    const int* __restrict__ rowptr = side ? a.rpB : a.rpA;
    const int* __restrict__ col = side ? a.colB : a.colA;
    ushort* __restrict__ out = side ? a.oB : a.oA;

    const int node = (bx * 256 + threadIdx.x) >> 6;
    const int lane = threadIdx.x & 63;
    if (node >= NN) return;
    const int beg = rowptr[node], end = rowptr[node + 1];
    float acc = bf2f(x[(size_t)node * 64 + lane]);
    int e = beg;
    for (; e + 7 < end; e += 8) {
        int s[8];
        #pragma unroll
        for (int k = 0; k < 8; ++k) s[k] = col[e + k];
        float v[8];
        #pragma unroll
        for (int k = 0; k < 8; ++k) v[k] = bf2f(x[(size_t)s[k] * 64 + lane]);
        #pragma unroll
        for (int k = 0; k < 8; ++k) acc += v[k];
    }
    for (; e + 3 < end; e += 4) {
        const int s0 = col[e], s1 = col[e + 1], s2 = col[e + 2], s3 = col[e + 3];
        acc += bf2f(x[(size_t)s0 * 64 + lane]) + bf2f(x[(size_t)s1 * 64 + lane])
             + bf2f(x[(size_t)s2 * 64 + lane]) + bf2f(x[(size_t)s3 * 64 + lane]);
    }
    for (; e < end; ++e) acc += bf2f(x[(size_t)col[e] * 64 + lane]);
    out[(size_t)node * 64 + lane] = (ushort)f2b(acc);
}

// ---------------------------------------------------------------- post-GEMM gather (F=128, pure adds)
// 1 node/wave, lane = 2 cols (4B loads); 8->4->1 unroll for MLP
struct GPostArgs {
    const ushort *yA, *yB;
    const int *rpA, *rpB, *colA, *colB;
    ushort *rA, *rB;
};

__global__ __launch_bounds__(256) void gather_post(GPostArgs a) {
    const int side = blockIdx.x >= GBLK;
    const int bx = blockIdx.x - side * GBLK;
    const ushort* __restrict__ y = side ? a.yB : a.yA;
    const int* __restrict__ rowptr = side ? a.rpB : a.rpA;
    const int* __restrict__ col = side ? a.colB : a.colA;
    ushort* __restrict__ r = side ? a.rB : a.rA;

    const int node = (bx * 256 + threadIdx.x) >> 6;
    const int lane = threadIdx.x & 63;
    if (node >= NN) return;
    const int beg = rowptr[node], end = rowptr[node + 1];
    const int c2 = lane * 2;

    const unsigned int u0 = *(const unsigned int*)&y[(size_t)node * 128 + c2];
    float ax = bf2f(u0 & 0xffffu), ay = bf2f(u0 >> 16);
    int e = beg;
    for (; e + 7 < end; e += 8) {
        int s[8];
        #pragma unroll
        for (int k = 0; k < 8; ++k) s[k] = col[e + k];
        unsigned int u[8];
        #pragma unroll
        for (int k = 0; k < 8; ++k) u[k] = *(const unsigned int*)&y[(size_t)s[k] * 128 + c2];
        #pragma unroll
        for (int k = 0; k < 8; ++k) {
            ax += bf2f(u[k] & 0xffffu);
            ay += bf2f(u[k] >> 16);
        }
    }
    for (; e + 3 < end; e += 4) {
        const int s0 = col[e], s1 = col[e + 1], s2 = col[e + 2], s3 = col[e + 3];
        const unsigned int ua = *(const unsigned int*)&y[(size_t)s0 * 128 + c2];
        const unsigned int ub = *(const unsigned int*)&y[(size_t)s1 * 128 + c2];
        const unsigned int uc = *(const unsigned int*)&y[(size_t)s2 * 128 + c2];
        const unsigned int ud = *(const unsigned int*)&y[(size_t)s3 * 128 + c2];
        ax += bf2f(ua & 0xffffu) + bf2f(ub & 0xffffu) + bf2f(uc & 0xffffu) + bf2f(ud & 0xffffu);
        ay += bf2f(ua >> 16) + bf2f(ub >> 16) + bf2f(uc >> 16) + bf2f(ud >> 16);
    }
    for (; e < end; ++e) {
        const unsigned int u = *(const unsigned int*)&y[(size_t)col[e] * 128 + c2];
        ax += bf2f(u & 0xffffu);
        ay += bf2f(u >> 16);
    }
    *(unsigned int*)&r[(size_t)node * 128 + c2] = f2b(ax) | (f2b(ay) << 16);
}

// ---------------------------------------------------------------- streaming BN stats (sum, sumsq) over bf16 [NN][128]
__global__ __launch_bounds__(256) void stats_pass(const ushort* __restrict__ hA,
                                                  const ushort* __restrict__ hB,
                                                  float* __restrict__ stA,
                                                  float* __restrict__ stB) {
    const int side = blockIdx.x >= NSB;
    const int bx = blockIdx.x - side * NSB;
    const ushort* __restrict__ h = side ? hB : hA;
    float* __restrict__ st = side ? stB : stA;
    const int t = threadIdx.x;
    const int c2 = (t & 63) * 2;
    const int rsub = t >> 6;            // 0..3
    const int rbeg = bx * 128;
    const int rend = min(rbeg + 128, NN);
    float s0 = 0.f, s1 = 0.f, q0 = 0.f, q1 = 0.f;
    for (int rr = rbeg + rsub; rr < rend; rr += 4) {
        const unsigned int u = *(const unsigned int*)&h[(size_t)rr * 128 + c2];
        const float e0 = bf2f(u & 0xffffu), e1 = bf2f(u >> 16);
        s0 += e0; s1 += e1;
        q0 = fmaf(e0, e0, q0); q1 = fmaf(e1, e1, q1);
    }
    __shared__ float red[512];
    red[rsub * 128 + c2] = s0; red[rsub * 128 + c2 + 1] = s1;
    __syncthreads();
    if (t < 128) {
        const float v = red[t] + red[128 + t] + red[256 + t] + red[384 + t];
        unsafeAtomicAdd(&st[t], v);
    }
    __syncthreads();
    red[rsub * 128 + c2] = q0; red[rsub * 128 + c2 + 1] = q1;
    __syncthreads();
    if (t < 128) {
        const float v = red[t] + red[128 + t] + red[256 + t] + red[384 + t];
        unsafeAtomicAdd(&st[128 + t], v);
    }
}

// ---------------------------------------------------------------- MFMA GEMM: C = f(M) @ W (bf16)
// f = APPLY_BN ? relu(bn(v)) (coefs from raw stats, applied during M staging) : identity.
// STATS: fused column stats of rounded C in epilogue (layer 1 only). No bias (zeros + BN shift-invariance).
struct GemmArgs {
    const ushort *mA, *mB;
    const ushort *WT;              // [128][FIN] bf16, transposed
    ushort *cA, *cB;
    float *stA, *stB;              // STATS: out; APPLY_BN: in (raw sums of M)
    const float *gamma, *beta;     // APPLY_BN only
};

template<int FIN, bool APPLY_BN, bool STATS>
__global__ __launch_bounds__(256) void gemm_mfma(GemmArgs g) {
    constexpr int FP = FIN + 8;          // padded LDS stride (bf16 units)
    constexpr int CPR = FIN / 8;         // 16B chunks per row
    const int side = blockIdx.x >= NBG;
    const int bx = blockIdx.x - side * NBG;
    const ushort* __restrict__ M = side ? g.mB : g.mA;
    ushort* __restrict__ C = side ? g.cB : g.cA;
    float* __restrict__ stats = side ? g.stB : g.stA;

    __shared__ ushort sh[64 * 136 + 128 * FP];
    ushort* Ml = sh;                     // M tile (stride FP); later C tile (stride 136)
    ushort* Wl = sh + 64 * 136;          // WT tile (stride FP); later stats red (fp32)

    const int t = threadIdx.x;
    const int w = t >> 6;                // wave 0..3
    const int l = t & 63;
    const int lr = l & 15;
    const int lg = l >> 4;
    const int r0 = bx * 64;

    // per-thread BN coefs for its 8 staging columns (k-dim = prev layer's feature dim)
    float ca[8], cb[8];
    if (APPLY_BN) {
        const float* __restrict__ st = stats;
        const int cc = (t % CPR) * 8;
        const float inv_n = 1.f / (float)NN;
        #pragma unroll
        for (int j = 0; j < 8; ++j) {
            const int c = cc + j;
            const float mu = st[c] * inv_n;
            const float var = st[128 + c] * inv_n - mu * mu;
            ca[j] = g.gamma[c] * rsqrtf(var + BN_EPS);
            cb[j] = fmaf(-mu, ca[j], g.beta[c]);
        }
    }

    // ---- stage f(M) (64 x FIN)
    #pragma unroll
    for (int it = 0; it < (64 * CPR) / 256; ++it) {
        const int cid = it * 256 + t;
        const int row = cid / CPR, cc = (cid % CPR) * 8;
        const int r = r0 + row;
        uint4 v = make_uint4(0u, 0u, 0u, 0u);
        if (r < NN) v = *(const uint4*)&M[(size_t)r * FIN + cc];
        if (APPLY_BN) {
            unsigned int vv[4] = {v.x, v.y, v.z, v.w};
            #pragma unroll
            for (int q2 = 0; q2 < 4; ++q2) {
                float e0 = bf2f(vv[q2] & 0xffffu), e1 = bf2f(vv[q2] >> 16);
                e0 = fmaxf(fmaf(e0, ca[2 * q2], cb[2 * q2]), 0.f);
                e1 = fmaxf(fmaf(e1, ca[2 * q2 + 1], cb[2 * q2 + 1]), 0.f);
                vv[q2] = f2b(e0) | (f2b(e1) << 16);
            }
            v = make_uint4(vv[0], vv[1], vv[2], vv[3]);
        }
        *(uint4*)&Ml[row * FP + cc] = v;
    }
    // ---- stage WT (128 x FIN)
    #pragma unroll
    for (int it = 0; it < (128 * CPR) / 256; ++it) {
        const int cid = it * 256 + t;
        const int c = cid / CPR, kk = (cid % CPR) * 8;
        *(uint4*)&Wl[c * FP + kk] = *(const uint4*)&g.WT[c * FIN + kk];
    }
    __syncthreads();

    f32x4 acc[4][2];
    #pragma unroll
    for (int fi = 0; fi < 4; ++fi)
        #pragma unroll
        for (int fj = 0; fj < 2; ++fj)
            acc[fi][fj] = (f32x4){0.f, 0.f, 0.f, 0.f};

    #pragma unroll
    for (int kc = 0; kc < FIN / 32; ++kc) {
        const int kb = kc * 32 + lg * 8;
        bf16x8 a[4], b[2];
        #pragma unroll
        for (int fi = 0; fi < 4; ++fi)
            a[fi] = *(const bf16x8*)&Ml[(fi * 16 + lr) * FP + kb];
        #pragma unroll
        for (int fj = 0; fj < 2; ++fj)
            b[fj] = *(const bf16x8*)&Wl[(w * 32 + fj * 16 + lr) * FP + kb];
        #pragma unroll
        for (int fi = 0; fi < 4; ++fi)
            #pragma unroll
            for (int fj = 0; fj < 2; ++fj)
                acc[fi][fj] = __builtin_amdgcn_mfma_f32_16x16x32_bf16(a[fi], b[fj], acc[fi][fj], 0, 0, 0);
    }
    __syncthreads();   // all LDS reads done; Ml/Wl reusable

    // ---- stage C tile (bf16) into Ml (stride 136); C/D layout: col=lane&15, row=(lane>>4)*4+j
    #pragma unroll
    for (int fi = 0; fi < 4; ++fi)
        #pragma unroll
        for (int fj = 0; fj < 2; ++fj)
            #pragma unroll
            for (int j = 0; j < 4; ++j) {
                const int row = fi * 16 + lg * 4 + j;
                const int c = w * 32 + fj * 16 + lr;
                Ml[row * 136 + c] = (ushort)f2b(acc[fi][fj][j]);
            }
    __syncthreads();

    // ---- epilogue: coalesced global store (+ BN partial stats for layer 1)
    const int ry = t >> 4, c0 = (t & 15) * 8;
    float sc[8], qc[8];
    if (STATS) {
        #pragma unroll
        for (int j = 0; j < 8; ++j) { sc[j] = 0.f; qc[j] = 0.f; }
    }
    #pragma unroll
    for (int i = 0; i < 4; ++i) {
        const int rr = ry * 4 + i;
        const int r = r0 + rr;
        if (r < NN) {
            const uint4 pk = *(const uint4*)&Ml[rr * 136 + c0];
            if (STATS) {
                const unsigned int uu[4] = {pk.x, pk.y, pk.z, pk.w};
                #pragma unroll
                for (int q2 = 0; q2 < 4; ++q2) {
                    const float e0 = bf2f(uu[q2] & 0xffffu);
                    const float e1 = bf2f(uu[q2] >> 16);
                    sc[2 * q2] += e0;       sc[2 * q2 + 1] += e1;
                    qc[2 * q2] = fmaf(e0, e0, qc[2 * q2]);
                    qc[2 * q2 + 1] = fmaf(e1, e1, qc[2 * q2 + 1]);
                }
            }
            *(uint4*)&C[(size_t)r * HID + c0] = pk;
        }
    }
    if (STATS) {
        float* red = (float*)Wl;             // 2048 floats
        #pragma unroll
        for (int j = 0; j < 8; ++j) red[ry * 128 + c0 + j] = sc[j];
        __syncthreads();
        if (t < 128) {
            float a = 0.f;
            #pragma unroll
            for (int k = 0; k < 16; ++k) a += red[k * 128 + t];
            unsafeAtomicAdd(&stats[t], a);
        }
        __syncthreads();
        #pragma unroll
        for (int j = 0; j < 8; ++j) red[ry * 128 + c0 + j] = qc[j];
        __syncthreads();
        if (t < 128) {
            float a = 0.f;
            #pragma unroll
            for (int k = 0; k < 16; ++k) a += red[k * 128 + t];
            unsafeAtomicAdd(&stats[128 + t], a);
        }
    }
}

// ---------------------------------------------------------------- pool, both sides, BN3+ReLU fused
struct PoolArgs {
    const ushort *hA, *hB;
    const void *btA, *btB;
    const float *stA, *stB;
    const float *gamma, *beta;
    float *pooled, *cnt;
    const int* flag;
};

__global__ __launch_bounds__(128) void pool16(PoolArgs p) {
    const int side = blockIdx.x >= NBG;
    const int bx = blockIdx.x - side * NBG;
    const ushort* __restrict__ h = side ? p.hB : p.hA;
    const void* __restrict__ batch = side ? p.btB : p.btA;
    const float* __restrict__ st = side ? p.stB : p.stA;
    float* pooled = p.pooled + side * NG * HID;
    float* cnt = p.cnt + side * NG;
    const bool is64 = (*p.flag != 0);
    const int c = threadIdx.x;

    const float inv_n = 1.f / (float)NN;
    const float mu = st[c] * inv_n;
    const float var = st[128 + c] * inv_n - mu * mu;
    const float ca = p.gamma[c] * rsqrtf(var + BN_EPS);
    const float cb = fmaf(-mu, ca, p.beta[c]);

    const int rbeg = bx * 64;
    if (rbeg >= NN) return;
    const int rend = min(rbeg + 64, NN);
    const int g0 = load_idx(batch, rbeg, is64);
    const int g1 = load_idx(batch, rend - 1, is64);
    if (g0 == g1) {
        float acc = 0.f;
        #pragma unroll 8
        for (int r = rbeg; r < rend; ++r)
            acc += fmaxf(fmaf(bf2f(h[r * HID + c]), ca, cb), 0.f);
        unsafeAtomicAdd(&pooled[g0 * HID + c], acc);
        if (c == 0) unsafeAtomicAdd(&cnt[g0], (float)(rend - rbeg));
        return;
    }
    int gprev = g0;
    float acc = 0.f; int run = 0;
    for (int r = rbeg; r < rend; ++r) {
        const int g = load_idx(batch, r, is64);
        if (g != gprev) {
            unsafeAtomicAdd(&pooled[gprev * HID + c], acc);
            if (c == 0) unsafeAtomicAdd(&cnt[gprev], (float)run);
            acc = 0.f; run = 0; gprev = g;
        }
        acc += fmaxf(fmaf(bf2f(h[r * HID + c]), ca, cb), 0.f);
        ++run;
    }
    unsafeAtomicAdd(&pooled[gprev * HID + c], acc);
    if (c == 0) unsafeAtomicAdd(&cnt[gprev], (float)run);
}

__global__ __launch_bounds__(64) void pool_proj(const float* __restrict__ pooled,
                                                const float* __restrict__ cnt,
                                                const float* __restrict__ Wf,
                                                const float* __restrict__ bf,
                                                float* __restrict__ v) {
    const int side = blockIdx.x >= NG;
    const int g = blockIdx.x - side * NG;
    const int c = threadIdx.x;  // 64
    const float* pp = pooled + side * NG * HID + g * HID;
    const float inv = 1.f / fmaxf(cnt[side * NG + g], 1.f);
    float acc = 0.f;
    for (int k = 0; k < HID; ++k) acc = fmaf(pp[k], Wf[k * EMB + c], acc);
    v[side * NG * EMB + g * EMB + c] = fmaf(acc, inv, bf[c]);
}

// ---------------------------------------------------------------- classifier head
__global__ __launch_bounds__(256) void classifier(const float* __restrict__ v1,
                                                  const float* __restrict__ v2,
                                                  const float* __restrict__ Wc1,
                                                  const float* __restrict__ bc1,
                                                  const float* __restrict__ Wc2,
                                                  const float* __restrict__ bc2,
                                                  float* __restrict__ out) {
    const int g = threadIdx.x;
    if (g >= NG) return;
    float d[EMB];
    #pragma unroll
    for (int c = 0; c < EMB; ++c) d[c] = fabsf(v1[g * EMB + c] - v2[g * EMB + c]);
    float o = bc2[0];
    for (int j = 0; j < 32; ++j) {
        float h = bc1[j];
        #pragma unroll
        for (int c = 0; c < EMB; ++c) h = fmaf(d[c], Wc1[c * 32 + j], h);
        h = fmaxf(h, 0.f);
        o = fmaf(h, Wc2[j], o);
    }
    out[g] = 1.f / (1.f + expf(-o));
}

// ---------------------------------------------------------------- launch
extern "C" void kernel_launch(void* const* d_in, const int* in_sizes, int n_in,
                              void* d_out, int out_size, void* d_ws, size_t ws_size,
                              hipStream_t stream) {
    const float* x1 = (const float*)d_in[0];
    const float* x2 = (const float*)d_in[1];
    const void* ei1 = d_in[2];
    const void* ei2 = d_in[3];
    const void* bt1 = d_in[4];
    const void* bt2 = d_in[5];
    const float* W[3]  = {(const float*)d_in[6],  (const float*)d_in[10], (const float*)d_in[14]};
    const float* gg[3] = {(const float*)d_in[8],  (const float*)d_in[12], (const float*)d_in[16]};
    const float* be[3] = {(const float*)d_in[9],  (const float*)d_in[13], (const float*)d_in[17]};
    const float* Wf  = (const float*)d_in[18];
    const float* bfv = (const float*)d_in[19];
    const float* Wc1 = (const float*)d_in[20];
    const float* bc1 = (const float*)d_in[21];
    const float* Wc2 = (const float*)d_in[22];
    const float* bc2 = (const float*)d_in[23];

    // ---- workspace carve-up (256B-aligned)
    char* cur = (char*)d_ws;
    auto alloc = [&](size_t bytes) -> void* {
        void* p = cur;
        cur += (bytes + 255) & ~(size_t)255;
        return p;
    };
    ushort* P0 = (ushort*)alloc((size_t)NN * HID * 2);   // side0: x16 / r1 / r2 / r3
    ushort* P1 = (ushort*)alloc((size_t)NN * HID * 2);
    ushort* Q0 = (ushort*)alloc((size_t)NN * HID * 2);   // side0: agg1 / y2 / y3
    ushort* Q1 = (ushort*)alloc((size_t)NN * HID * 2);
    int* deg2   = (int*)alloc((size_t)2 * NN * 4);
    int* rpA    = (int*)alloc((size_t)(NN + 1) * 4);
    int* rpB    = (int*)alloc((size_t)(NN + 1) * 4);
    int* curA   = (int*)alloc((size_t)NN * 4);
    int* curB   = (int*)alloc((size_t)NN * 4);
    int* bsum   = (int*)alloc(256 * 4);
    int* boff   = (int*)alloc(256 * 4);
    int* colA   = (int*)alloc((size_t)NE * 4);
    int* colB   = (int*)alloc((size_t)NE * 4);
    int* es1    = (int*)alloc((size_t)NE * 4);
    int* ed1    = (int*)alloc((size_t)NE * 4);
    int* es2    = (int*)alloc((size_t)NE * 4);
    int* ed2    = (int*)alloc((size_t)NE * 4);
    int* flag   = (int*)alloc(64);
    ushort* WT1 = (ushort*)alloc(128 * 64 * 2);
    ushort* WT2 = (ushort*)alloc(128 * 128 * 2);
    ushort* WT3 = (ushort*)alloc(128 * 128 * 2);
    float* zreg = (float*)alloc((size_t)(6 * 256 + 2 * NG * HID + 2 * NG) * 4);
    float* stats  = zreg;                         // 6 x 256 (sum[128], sumsq[128])
    float* pooled = stats + 6 * 256;              // 2 x G x 128
    float* cnt    = pooled + 2 * NG * HID;        // 2 x G
    float* vv     = (float*)alloc((size_t)2 * NG * EMB * 4);
    int* degA = deg2, *degB = deg2 + NN;

    hipMemsetAsync(deg2, 0, (size_t)2 * NN * 4, stream);
    hipMemsetAsync(zreg, 0, (size_t)(6 * 256 + 2 * NG * HID + 2 * NG) * 4, stream);
    detect_i64_kernel<<<1, 64, 0, stream>>>(ei1, flag);
    convert_x<<<(2 * NN * 16) / 256, 256, 0, stream>>>(x1, x2, P0, P1);
    prep_weights<<<160, 256, 0, stream>>>(W[0], W[1], W[2], WT1, WT2, WT3);

    // ---- CSR build: fused convert+hist, scans, XCD-partitioned int32 fill
    const int EB2 = (2 * NE + 255) / 256;
    convert_edges<<<EB2, 256, 0, stream>>>(ei1, ei2, es1, ed1, es2, ed2, degA, degB, flag);
    scan_block_sums2<<<2 * SNB, 256, 0, stream>>>(degA, degB, bsum);
    scan_bsums2<<<2, 128, 0, stream>>>(bsum, boff, rpA, rpB);
    scan_fill2<<<2 * SNB, 256, 0, stream>>>(degA, degB, boff, rpA, rpB, curA, curB);
    csr_fill_part<<<8 * 2 * NCH, 256, 0, stream>>>(es1, ed1, es2, ed2, curA, curB, colA, colB);

    float* st1A = stats + 0 * 256, *st1B = stats + 1 * 256;   // stats of r1 (BN1)
    float* st2A = stats + 2 * 256, *st2B = stats + 3 * 256;   // stats of r2 (BN2)
    float* st3A = stats + 4 * 256, *st3B = stats + 5 * 256;   // stats of r3 (BN3)

    // ---- layer 1: agg1 = (1+A)x16  P->Q ;  r1 = agg1 @ W1 -> P (+stats1)
    {
        G64Args a = {P0, P1, rpA, rpB, colA, colB, Q0, Q1};
        gather64k<<<2 * GBLK, 256, 0, stream>>>(a);
        GemmArgs g = {Q0, Q1, WT1, P0, P1, st1A, st1B, nullptr, nullptr};
        gemm_mfma<64, false, true><<<2 * NBG, 256, 0, stream>>>(g);
    }
    // ---- layer 2: y2 = f1(r1) @ W2  P->Q ;  r2 = (1+A)y2 -> P ; stats2
    {
        GemmArgs g = {P0, P1, WT2, Q0, Q1, st1A, st1B, gg[0], be[0]};
        gemm_mfma<128, true, false><<<2 * NBG, 256, 0, stream>>>(g);
        GPostArgs a = {Q0, Q1, rpA, rpB, colA, colB, P0, P1};
        gather_post<<<2 * GBLK, 256, 0, stream>>>(a);
        stats_pass<<<2 * NSB, 256, 0, stream>>>(P0, P1, st2A, st2B);
    }
    // ---- layer 3: y3 = f2(r2) @ W3  P->Q ;  r3 = (1+A)y3 -> P ; stats3
    {
        GemmArgs g = {P0, P1, WT3, Q0, Q1, st2A, st2B, gg[1], be[1]};
        gemm_mfma<128, true, false><<<2 * NBG, 256, 0, stream>>>(g);
        GPostArgs a = {Q0, Q1, rpA, rpB, colA, colB, P0, P1};
        gather_post<<<2 * GBLK, 256, 0, stream>>>(a);
        stats_pass<<<2 * NSB, 256, 0, stream>>>(P0, P1, st3A, st3B);
    }
    // ---- pool (BN3+ReLU fused), projection, classifier
    {
        PoolArgs p = {P0, P1, bt1, bt2, st3A, st3B, gg[2], be[2], pooled, cnt, flag};
        pool16<<<2 * NBG, 128, 0, stream>>>(p);
    }
    pool_proj<<<2 * NG, 64, 0, stream>>>(pooled, cnt, Wf, bfv, vv);
    classifier<<<1, 256, 0, stream>>>(vv, vv + NG * EMB, Wc1, bc1, Wc2, bc2, (float*)d_out);
}